// Round 13
// baseline (245.764 us; speedup 1.0000x reference)
//
#include <hip/hip_runtime.h>
#include <hip/hip_bf16.h>

#define S_LEN 2048
#define D_DIM 1024
#define H_NUM 16
#define HD_DIM 64
#define GH_DIM 64
#define FFN_H 2730
#define FFNP  2816          // FFN_H padded to multiple of 128 (zero-filled)
#define CTX_W 512
#define L2LAM -0.00144341687f   // log2(0.999)
#define QBLK 64
#define KBLK 64
#define ALDK 76             // LDS row stride (152B): write-conflict-free, reads <=2-way
#define QSCALE 0.1803368801111731f  // 0.125 * log2(e): scores come out ready for exp2

typedef unsigned short u16;
typedef __attribute__((ext_vector_type(8))) short bf16x8_t;
typedef __attribute__((ext_vector_type(4))) float f32x4_t;

__device__ inline float wave_sum(float v) {
    for (int off = 32; off; off >>= 1) v += __shfl_xor(v, off);
    return v;
}
// f32 -> bf16 (RNE) via the HW pack instruction: 1 VALU op.
__device__ inline u16 f2bf(float f) {
    unsigned r;
    asm("v_cvt_pk_bf16_f32 %0, %1, %2" : "=v"(r) : "v"(f), "v"(f));
    return (u16)r;
}
// pack two f32 -> u32 of 2 bf16 (lo, hi): 1 VALU op.
__device__ inline unsigned f2bf2(float lo, float hi) {
    unsigned r;
    asm("v_cvt_pk_bf16_f32 %0, %1, %2" : "=v"(r) : "v"(lo), "v"(hi));
    return r;
}
__device__ inline float bf2f(u16 u) {
    return __uint_as_float(((unsigned int)u) << 16);
}
__device__ inline void gload16(const void* g, void* l) {
    __builtin_amdgcn_global_load_lds(
        (const __attribute__((address_space(1))) void*)g,
        (__attribute__((address_space(3))) void*)l, 16, 0, 0);
}

// ---------------- RMSNorm (fp32 in -> bf16 out) -----------------------------
__global__ __launch_bounds__(256) void rmsnorm_bf_kernel(const float* __restrict__ in,
    const float* __restrict__ w, u16* __restrict__ out)
{
    int row = blockIdx.x;
    const float4* ir = reinterpret_cast<const float4*>(in + (size_t)row * D_DIM);
    float4 v = ir[threadIdx.x];
    float ss = v.x*v.x + v.y*v.y + v.z*v.z + v.w*v.w;
    ss = wave_sum(ss);
    __shared__ float wsum[4];
    if ((threadIdx.x & 63) == 0) wsum[threadIdx.x >> 6] = ss;
    __syncthreads();
    float tot = wsum[0] + wsum[1] + wsum[2] + wsum[3];
    float scale = rsqrtf(tot / (float)D_DIM + 1e-6f);
    const float4* wr = reinterpret_cast<const float4*>(w);
    float4 wv = wr[threadIdx.x];
    uint2 o;
    o.x = f2bf2(v.x * scale * wv.x, v.y * scale * wv.y);
    o.y = f2bf2(v.z * scale * wv.z, v.w * scale * wv.w);
    *reinterpret_cast<uint2*>(out + (size_t)row * D_DIM + threadIdx.x * 4) = o;
}

// ------------- fused all-weight transpose+convert (5 segments, 1 launch) ----
__global__ __launch_bounds__(256) void transpose_all_kernel(
    const float* __restrict__ w_qkv, const float* __restrict__ w_o,
    const float* __restrict__ w1, const float* __restrict__ w3,
    const float* __restrict__ w2f, u16* __restrict__ wqT,
    u16* __restrict__ woT, u16* __restrict__ w13T, u16* __restrict__ w2T)
{
    __shared__ float tile[32][33];
    int b = blockIdx.x;
    const float* src; u16* dst;
    int srcK, srcN, Kp, rowOff, rowMul, nbx;
    if (b < 3072)      {           src = w_qkv; dst = wqT;  srcK = 1024; srcN = 3072; Kp = 1024; rowOff = 0; rowMul = 1; nbx = 96; }
    else if (b < 4096) { b -= 3072; src = w_o;  dst = woT;  srcK = 1024; srcN = 1024; Kp = 1024; rowOff = 0; rowMul = 1; nbx = 32; }
    else if (b < 6912) { b -= 4096; src = w1;   dst = w13T; srcK = 1024; srcN = 2730; Kp = 1024; rowOff = 0; rowMul = 2; nbx = 88; }
    else if (b < 9728) { b -= 6912; src = w3;   dst = w13T; srcK = 1024; srcN = 2730; Kp = 1024; rowOff = 1; rowMul = 2; nbx = 88; }
    else               { b -= 9728; src = w2f;  dst = w2T;  srcK = 2730; srcN = 1024; Kp = 2816; rowOff = 0; rowMul = 1; nbx = 32; }
    int n0 = (b % nbx) * 32, k0 = (b / nbx) * 32;
    int tx = threadIdx.x & 31, ty = threadIdx.x >> 5;
    #pragma unroll
    for (int p = 0; p < 4; ++p) {
        int kk = ty + p * 8;
        int r = k0 + kk, c = n0 + tx;
        tile[kk][tx] = (r < srcK && c < srcN) ? src[(size_t)r * srcN + c] : 0.f;
    }
    __syncthreads();
    #pragma unroll
    for (int p = 0; p < 4; ++p) {
        int nn = ty + p * 8;
        dst[(size_t)(rowOff + (n0 + nn) * rowMul) * Kp + k0 + tx] = f2bf(tile[tx][nn]);
    }
}

// ------------- transpose bf16 K,V: (H,S,64) -> (H,64,S), s-cols permuted ----
// Within each 64-tile of s, column k holds real s-index pi^-1(k) where
// pi(s) = (s&15)*4 + (s>>4). Matches the vectorized P-store layout.
__global__ __launch_bounds__(256) void transpose_kv_kernel(
    const u16* __restrict__ kh, const u16* __restrict__ vh,
    u16* __restrict__ khT, u16* __restrict__ vhT)
{
    __shared__ u16 tk[64][ALDK];
    __shared__ u16 tv[64][ALDK];
    int h = blockIdx.y;
    int s0 = blockIdx.x * 64;
    int tid = threadIdx.x;
    int r = tid >> 2, cc = (tid & 3) * 16;
    const u16* kp = kh + ((size_t)h * S_LEN + s0 + r) * HD_DIM + cc;
    const u16* vp = vh + ((size_t)h * S_LEN + s0 + r) * HD_DIM + cc;
    *(bf16x8_t*)&tk[r][cc]     = *(const bf16x8_t*)kp;
    *(bf16x8_t*)&tk[r][cc + 8] = *(const bf16x8_t*)(kp + 8);
    *(bf16x8_t*)&tv[r][cc]     = *(const bf16x8_t*)vp;
    *(bf16x8_t*)&tv[r][cc + 8] = *(const bf16x8_t*)(vp + 8);
    __syncthreads();
    union { u16 u[16]; bf16x8_t v[2]; } ok, ov;
    #pragma unroll
    for (int e = 0; e < 16; ++e) {
        int ksrc = (e & 3) * 16 + (tid & 3) * 4 + (e >> 2);
        ok.u[e] = tk[ksrc][r]; ov.u[e] = tv[ksrc][r];
    }
    u16* kd = khT + ((size_t)h * HD_DIM + r) * S_LEN + s0 + cc;
    u16* vd = vhT + ((size_t)h * HD_DIM + r) * S_LEN + s0 + cc;
    *(bf16x8_t*)kd       = ok.v[0];
    *(bf16x8_t*)(kd + 8) = ok.v[1];
    *(bf16x8_t*)vd       = ov.v[0];
    *(bf16x8_t*)(vd + 8) = ov.v[1];
}

// ---------------- bf16 MFMA GEMM, 128-col tiles ------------------------------
// MODE 1: bf16 out.  MODE 2: paired silu-mul, bf16 out width N/2.
template<int BM, int MODE>
__global__ __launch_bounds__(256) void gemm_bb_kernel(
    const u16* __restrict__ A, const u16* __restrict__ B,
    u16* __restrict__ Cb, int M, int N, int K)
{
    constexpr int MREP = BM / 32;
    constexpr int ACH  = BM / 32;
    __shared__ u16 As[BM * 64];
    __shared__ u16 Bs[128 * 64];
    int tid = threadIdx.x, lane = tid & 63, wid = tid >> 6;
    int wr = wid >> 1, wc = wid & 1;
    int row0 = blockIdx.y * BM, col0 = blockIdx.x * 128;
    int l8 = lane >> 3, l7 = lane & 7;
    f32x4_t acc[MREP][4];
    #pragma unroll
    for (int i = 0; i < MREP; ++i)
        #pragma unroll
        for (int j = 0; j < 4; ++j) acc[i][j] = (f32x4_t)0.f;

    int fr = lane & 15, fo = (lane >> 4) * 8;
    for (int k0 = 0; k0 < K; k0 += 64) {
        #pragma unroll
        for (int i = 0; i < ACH; ++i) {
            int ch = wid * ACH + i;
            const u16* ga = A + (size_t)(row0 + ch * 8 + l8) * K + k0 + l7 * 8;
            gload16(ga, &As[ch * 512]);
        }
        #pragma unroll
        for (int i = 0; i < 4; ++i) {
            int ch = wid * 4 + i;
            const u16* gb = B + (size_t)(col0 + ch * 8 + l8) * K + k0 + l7 * 8;
            gload16(gb, &Bs[ch * 512]);
        }
        __syncthreads();
        __builtin_amdgcn_s_setprio(1);
        #pragma unroll
        for (int khf = 0; khf < 2; ++khf) {
            bf16x8_t bfrag[4];
            #pragma unroll
            for (int ni = 0; ni < 4; ++ni)
                bfrag[ni] = *(const bf16x8_t*)&Bs[(wc * 64 + ni * 16 + fr) * 64 + khf * 32 + fo];
            #pragma unroll
            for (int mi = 0; mi < MREP; ++mi) {
                bf16x8_t af = *(const bf16x8_t*)&As[(wr * (BM / 2) + mi * 16 + fr) * 64 + khf * 32 + fo];
                #pragma unroll
                for (int ni = 0; ni < 4; ++ni)
                    acc[mi][ni] = __builtin_amdgcn_mfma_f32_16x16x32_bf16(
                        af, bfrag[ni], acc[mi][ni], 0, 0, 0);
            }
        }
        __builtin_amdgcn_s_setprio(0);
        __syncthreads();
    }
    int dr = (lane >> 4) * 4, dc = lane & 15;
    #pragma unroll
    for (int mi = 0; mi < MREP; ++mi) {
        int gr = row0 + wr * (BM / 2) + mi * 16 + dr;
        #pragma unroll
        for (int ni = 0; ni < 4; ++ni) {
            int gc = col0 + wc * 64 + ni * 16 + dc;
            #pragma unroll
            for (int j = 0; j < 4; ++j) {
                float v = acc[mi][ni][j];
                if (MODE == 1) {
                    Cb[(size_t)(gr + j) * N + gc] = f2bf(v);
                } else {
                    float partner = __shfl_xor(v, 1);
                    float a1 = (dc & 1) ? partner : v;
                    float a3 = (dc & 1) ? v : partner;
                    float rr = a1 / (1.f + __expf(-a1)) * a3;
                    if (!(dc & 1))
                        Cb[(size_t)(gr + j) * (N >> 1) + (gc >> 1)] = f2bf(rr);
                }
            }
        }
    }
}

// ------- bf16 MFMA GEMM, 64x64 tiles, split-K, atomic fp32 accumulate -------
// Cf must be pre-initialized with the residual; partial sums are atomicAdd'ed.
__global__ __launch_bounds__(256) void gemm64_splitk_kernel(
    const u16* __restrict__ A, const u16* __restrict__ B,
    float* __restrict__ Cf, int M, int N, int K, int kSplit)
{
    __shared__ u16 As[64 * 64];
    __shared__ u16 Bs[64 * 64];
    int tid = threadIdx.x, lane = tid & 63, wid = tid >> 6;
    int wr = wid >> 1, wc = wid & 1;
    int row0 = blockIdx.y * 64, col0 = blockIdx.x * 64;
    int kChunk = K / kSplit;
    int kBeg = blockIdx.z * kChunk, kEnd = kBeg + kChunk;
    int l8 = lane >> 3, l7 = lane & 7;
    f32x4_t acc[2][2];
    #pragma unroll
    for (int i = 0; i < 2; ++i)
        #pragma unroll
        for (int j = 0; j < 2; ++j) acc[i][j] = (f32x4_t)0.f;
    int fr = lane & 15, fo = (lane >> 4) * 8;
    for (int k0 = kBeg; k0 < kEnd; k0 += 64) {
        #pragma unroll
        for (int i = 0; i < 2; ++i) {
            int ch = wid * 2 + i;
            const u16* ga = A + (size_t)(row0 + ch * 8 + l8) * K + k0 + l7 * 8;
            gload16(ga, &As[ch * 512]);
            const u16* gb = B + (size_t)(col0 + ch * 8 + l8) * K + k0 + l7 * 8;
            gload16(gb, &Bs[ch * 512]);
        }
        __syncthreads();
        __builtin_amdgcn_s_setprio(1);
        #pragma unroll
        for (int khf = 0; khf < 2; ++khf) {
            bf16x8_t bfrag[2];
            #pragma unroll
            for (int ni = 0; ni < 2; ++ni)
                bfrag[ni] = *(const bf16x8_t*)&Bs[(wc * 32 + ni * 16 + fr) * 64 + khf * 32 + fo];
            #pragma unroll
            for (int mi = 0; mi < 2; ++mi) {
                bf16x8_t af = *(const bf16x8_t*)&As[(wr * 32 + mi * 16 + fr) * 64 + khf * 32 + fo];
                #pragma unroll
                for (int ni = 0; ni < 2; ++ni)
                    acc[mi][ni] = __builtin_amdgcn_mfma_f32_16x16x32_bf16(
                        af, bfrag[ni], acc[mi][ni], 0, 0, 0);
            }
        }
        __builtin_amdgcn_s_setprio(0);
        __syncthreads();
    }
    int dr = (lane >> 4) * 4, dc = lane & 15;
    #pragma unroll
    for (int mi = 0; mi < 2; ++mi) {
        int gr = row0 + wr * 32 + mi * 16 + dr;
        #pragma unroll
        for (int ni = 0; ni < 2; ++ni) {
            int gc = col0 + wc * 32 + ni * 16 + dc;
            #pragma unroll
            for (int j = 0; j < 4; ++j) {
                size_t off = (size_t)(gr + j) * N + gc;
                atomicAdd(&Cf[off], acc[mi][ni][j]);
            }
        }
    }
}

// ------------- split qkv(bf16) + qk rmsnorm + RoPE (4 waves/block) ----------
__global__ __launch_bounds__(256) void split_rope_kernel(
    const u16* __restrict__ qkv, const float* __restrict__ qw,
    const float* __restrict__ kw, float* __restrict__ qhp,
    u16* __restrict__ khp, u16* __restrict__ vhp)
{
    int wq = threadIdx.x >> 6, d = threadIdx.x & 63;
    int s = blockIdx.x * 4 + wq, h = blockIdx.y;
    size_t base = (size_t)s * (3 * D_DIM) + h * HD_DIM + d;
    float qv = bf2f(qkv[base]);
    float kv = bf2f(qkv[base + D_DIM]);
    u16  vv = qkv[base + 2 * D_DIM];
    float sq = wave_sum(qv * qv);
    float qn = qv * rsqrtf(sq / (float)HD_DIM + 1e-6f) * qw[d];
    float sk = wave_sum(kv * kv);
    float kn = kv * rsqrtf(sk / (float)HD_DIM + 1e-6f) * kw[d];
    int j = d & 31;
    float inv = expf(-(float)j * (9.2103403719761836f / 32.0f));
    float ang = (float)s * inv;
    float cs = cosf(ang), sn = sinf(ang);
    float qp = __shfl_xor(qn, 32);
    float kp = __shfl_xor(kn, 32);
    float sgn = (d < 32) ? -1.f : 1.f;
    float qo = qn * cs + sgn * qp * sn;
    float ko = kn * cs + sgn * kp * sn;
    size_t ob = ((size_t)h * S_LEN + s) * HD_DIM + d;
    qhp[ob] = qo; khp[ob] = f2bf(ko); vhp[ob] = vv;
}

// ------------- gamma gate (4-wave parallel, 1 token/block) ------------------
__global__ __launch_bounds__(256) void gamma_kernel(const u16* __restrict__ h,
    const float* __restrict__ w1, const float* __restrict__ w2,
    float* __restrict__ gamma)
{
    __shared__ float hl[D_DIM];
    __shared__ float part[4][GH_DIM];
    int s = blockIdx.x, tid = threadIdx.x, lane = tid & 63, w = tid >> 6;
    {
        ushort4 v = *(const ushort4*)(h + (size_t)s * D_DIM + tid * 4);
        hl[tid*4+0] = bf2f(v.x); hl[tid*4+1] = bf2f(v.y);
        hl[tid*4+2] = bf2f(v.z); hl[tid*4+3] = bf2f(v.w);
    }
    __syncthreads();
    float acc = 0.f;
    #pragma unroll 8
    for (int k = w * 256; k < w * 256 + 256; ++k)
        acc += hl[k] * w1[k * GH_DIM + lane];
    part[w][lane] = acc;
    __syncthreads();
    if (w == 0) {
        float tot = part[0][lane] + part[1][lane] + part[2][lane] + part[3][lane];
        float z = tot / (1.f + __expf(-tot));
        float y = z * w2[lane];
        float t2 = wave_sum(y);
        if (lane == 0) gamma[s] = 1.f / (1.f + __expf(-t2));
    }
}

// ============ FUSED omega-rule + flash attention ============================
// 1-D grid, XCD head-locality AND complementary qt pairing:
//   hi = bit8, h = (b&7)*2 + hi, qt = hi ? 31-s5 : s5.
// 1-tile double-buffered loops, no-max softmax, b64 P-stores via cvt_pk and
// the s-column permutation pi(s)=(s&15)*4+(s>>4) pre-applied to khT/vhT.
__global__ __launch_bounds__(256) void fused_omega_attn_kernel(
    const float* __restrict__ qhp, const u16* __restrict__ khp,
    const u16* __restrict__ khT, const u16* __restrict__ vhT,
    const float* __restrict__ gammab, const float* __restrict__ mp,
    const float* __restrict__ mg, u16* __restrict__ ao)
{
    __shared__ u16 Ks[2][KBLK][ALDK];
    __shared__ u16 Xt[2][KBLK][ALDK];
    __shared__ u16 Ps[QBLK][ALDK];
    const int tid = threadIdx.x, lane = tid & 63, wq = tid >> 6;
    const int b = blockIdx.x;
    const int hi = (b >> 8) & 1;
    const int h = ((b & 7) << 1) + hi;
    const int s5 = (b >> 3) & 31;
    const int qt = hi ? (31 - s5) : s5;
    const int q0 = qt * QBLK;
    const int fr = lane & 15, g4 = lane >> 4;
    const int fko = g4 * 8;
    const int c = fr, rg = g4;
    const int si = tid >> 2, sdb = (tid & 3) * 16;
    const size_t hS = (size_t)h * S_LEN;
    const size_t hD = (size_t)h * HD_DIM;

    int rowt[4]; float rowf[4];
    #pragma unroll
    for (int j = 0; j < 4; ++j) {
        rowt[j] = q0 + wq * 16 + rg * 4 + j;
        rowf[j] = exp2f((float)(wq * 16 + rg * 4 + j) * L2LAM);
    }
    // q_old A-fragments (bf16)
    bf16x8_t qf[2];
    {
        const float* qrow = qhp + (hS + q0 + wq * 16 + fr) * HD_DIM;
        #pragma unroll
        for (int u = 0; u < 2; ++u) {
            float4 a = *(const float4*)(qrow + u * 32 + fko);
            float4 bq = *(const float4*)(qrow + u * 32 + fko + 4);
            bf16x8_t f;
            f[0]=f2bf(a.x); f[1]=f2bf(a.y); f[2]=f2bf(a.z); f[3]=f2bf(a.w);
            f[4]=f2bf(bq.x); f[5]=f2bf(bq.y); f[6]=f2bf(bq.z); f[7]=f2bf(bq.w);
            qf[u] = f;
        }
    }
    // ---------------- omega phase (double-buffered) ----------------
    f32x4_t accc[4];
    #pragma unroll
    for (int n = 0; n < 4; ++n) accc[n] = (f32x4_t)0.f;
    float wsum[4] = {0.f, 0.f, 0.f, 0.f};
    const int kt0 = (q0 > (CTX_W - 1)) ? (q0 - (CTX_W - 1)) / KBLK : 0;
    {
        const u16* gk = khp + (hS + kt0 * KBLK + si) * HD_DIM + sdb;
        const u16* gx = khT + (hD + si) * S_LEN + kt0 * KBLK + sdb;
        *(bf16x8_t*)&Ks[0][si][sdb]     = *(const bf16x8_t*)gk;
        *(bf16x8_t*)&Ks[0][si][sdb + 8] = *(const bf16x8_t*)(gk + 8);
        *(bf16x8_t*)&Xt[0][si][sdb]     = *(const bf16x8_t*)gx;
        *(bf16x8_t*)&Xt[0][si][sdb + 8] = *(const bf16x8_t*)(gx + 8);
    }
    __syncthreads();
    int cur = 0;
    for (int kt = kt0; kt <= qt; ++kt) {
        const int k0 = kt * KBLK;
        const bool hn = (kt < qt);
        bf16x8_t nk0, nk1, nx0, nx1;
        if (hn) {
            const u16* gk = khp + (hS + k0 + KBLK + si) * HD_DIM + sdb;
            const u16* gx = khT + (hD + si) * S_LEN + k0 + KBLK + sdb;
            nk0 = *(const bf16x8_t*)gk; nk1 = *(const bf16x8_t*)(gk + 8);
            nx0 = *(const bf16x8_t*)gx; nx1 = *(const bf16x8_t*)(gx + 8);
        }
        f32x4_t s[4];
        #pragma unroll
        for (int n = 0; n < 4; ++n) s[n] = (f32x4_t)0.f;
        __builtin_amdgcn_s_setprio(1);
        #pragma unroll
        for (int u = 0; u < 2; ++u)
            #pragma unroll
            for (int n = 0; n < 4; ++n) {
                bf16x8_t kb = *(const bf16x8_t*)&Ks[cur][n * 16 + fr][u * 32 + fko];
                s[n] = __builtin_amdgcn_mfma_f32_16x16x32_bf16(qf[u], kb, s[n], 0, 0, 0);
            }
        __builtin_amdgcn_s_setprio(0);
        const bool boundary = (kt == kt0) || (kt == qt);
        float colf[4];
        #pragma unroll
        for (int n = 0; n < 4; ++n) {
            int icol = k0 + n * 16 + c;
            colf[n] = exp2f((float)(q0 - icol) * L2LAM) * gammab[icol];
        }
        #pragma unroll
        for (int j = 0; j < 4; ++j) {
            float pv[4];
            #pragma unroll
            for (int n = 0; n < 4; ++n) {
                float w;
                if (boundary) {
                    int delta = rowt[j] - (k0 + n * 16 + c);
                    w = (delta >= 0 && delta < CTX_W) ? rowf[j] * colf[n] : 0.f;
                } else {
                    w = rowf[j] * colf[n];
                }
                wsum[j] += w;
                pv[n] = w * s[n][j];
            }
            uint2 pk;
            pk.x = f2bf2(pv[0], pv[1]);
            pk.y = f2bf2(pv[2], pv[3]);
            *(uint2*)&Ps[wq * 16 + rg * 4 + j][c * 4] = pk;   // ds_write_b64
        }
        __builtin_amdgcn_s_setprio(1);
        #pragma unroll
        for (int u = 0; u < 2; ++u) {
            bf16x8_t pa = *(const bf16x8_t*)&Ps[wq * 16 + fr][u * 32 + fko];
            #pragma unroll
            for (int n = 0; n < 4; ++n) {
                bf16x8_t kb = *(const bf16x8_t*)&Xt[cur][n * 16 + fr][u * 32 + fko];
                accc[n] = __builtin_amdgcn_mfma_f32_16x16x32_bf16(pa, kb, accc[n], 0, 0, 0);
            }
        }
        __builtin_amdgcn_s_setprio(0);
        if (hn) {
            int nxt = cur ^ 1;
            *(bf16x8_t*)&Ks[nxt][si][sdb]     = nk0;
            *(bf16x8_t*)&Ks[nxt][si][sdb + 8] = nk1;
            *(bf16x8_t*)&Xt[nxt][si][sdb]     = nx0;
            *(bf16x8_t*)&Xt[nxt][si][sdb + 8] = nx1;
        }
        __syncthreads();
        cur ^= 1;
    }
    // persist = Q @ M_p^T
    f32x4_t pacc[4];
    #pragma unroll
    for (int n = 0; n < 4; ++n) pacc[n] = (f32x4_t)0.f;
    const float* mph = mp + hD * HD_DIM;
    #pragma unroll
    for (int u = 0; u < 2; ++u)
        #pragma unroll
        for (int n = 0; n < 4; ++n) {
            const float* br = mph + (size_t)(n * 16 + fr) * HD_DIM + u * 32 + fko;
            float4 a = *(const float4*)br;
            float4 bq = *(const float4*)(br + 4);
            bf16x8_t f;
            f[0]=f2bf(a.x); f[1]=f2bf(a.y); f[2]=f2bf(a.z); f[3]=f2bf(a.w);
            f[4]=f2bf(bq.x); f[5]=f2bf(bq.y); f[6]=f2bf(bq.z); f[7]=f2bf(bq.w);
            pacc[n] = __builtin_amdgcn_mfma_f32_16x16x32_bf16(qf[u], f, pacc[n], 0, 0, 0);
        }
    #pragma unroll
    for (int j = 0; j < 4; ++j) {
        wsum[j] += __shfl_xor(wsum[j], 1);
        wsum[j] += __shfl_xor(wsum[j], 2);
        wsum[j] += __shfl_xor(wsum[j], 4);
        wsum[j] += __shfl_xor(wsum[j], 8);
    }
    float gate = 1.f / (1.f + __expf(-mg[0]));
    float keep = 1.f - gate;
    // q_new (pre-scaled by 0.125*log2e) -> wave-private rows (d-domain, scalar)
    #pragma unroll
    for (int n = 0; n < 4; ++n) {
        #pragma unroll
        for (int j = 0; j < 4; ++j) {
            float qold = qhp[(hS + rowt[j]) * HD_DIM + n * 16 + c];
            float qn = keep * qold + gate * (pacc[n][j] + accc[n][j]) / (1.f + wsum[j]);
            Ps[wq * 16 + rg * 4 + j][n * 16 + c] = f2bf(qn * QSCALE);
        }
    }
    bf16x8_t qf2[2];
    #pragma unroll
    for (int u = 0; u < 2; ++u)
        qf2[u] = *(const bf16x8_t*)&Ps[wq * 16 + fr][u * 32 + fko];

    // ---------------- attention phase (double-buffered, no-max softmax) -----
    f32x4_t acco[4];
    #pragma unroll
    for (int n = 0; n < 4; ++n) acco[n] = (f32x4_t)0.f;
    float l_run[4] = {0.f, 0.f, 0.f, 0.f};
    {   // prologue: stage tile 0 into buffer 0 (all omega reads done)
        const u16* gk = khp + (hS + si) * HD_DIM + sdb;
        const u16* gv = vhT + (hD + si) * S_LEN + sdb;
        *(bf16x8_t*)&Ks[0][si][sdb]     = *(const bf16x8_t*)gk;
        *(bf16x8_t*)&Ks[0][si][sdb + 8] = *(const bf16x8_t*)(gk + 8);
        *(bf16x8_t*)&Xt[0][si][sdb]     = *(const bf16x8_t*)gv;
        *(bf16x8_t*)&Xt[0][si][sdb + 8] = *(const bf16x8_t*)(gv + 8);
    }
    __syncthreads();
    cur = 0;
    for (int kt = 0; kt <= qt; ++kt) {
        const int k0 = kt * KBLK;
        const bool hn = (kt < qt);
        bf16x8_t nk0, nk1, nv0, nv1;
        if (hn) {
            const u16* gk = khp + (hS + k0 + KBLK + si) * HD_DIM + sdb;
            const u16* gv = vhT + (hD + si) * S_LEN + k0 + KBLK + sdb;
            nk0 = *(const bf16x8_t*)gk; nk1 = *(const bf16x8_t*)(gk + 8);
            nv0 = *(const bf16x8_t*)gv; nv1 = *(const bf16x8_t*)(gv + 8);
        }
        f32x4_t s[4];
        #pragma unroll
        for (int n = 0; n < 4; ++n) s[n] = (f32x4_t)0.f;
        __builtin_amdgcn_s_setprio(1);
        #pragma unroll
        for (int u = 0; u < 2; ++u)
            #pragma unroll
            for (int n = 0; n < 4; ++n) {
                bf16x8_t kb = *(const bf16x8_t*)&Ks[cur][n * 16 + fr][u * 32 + fko];
                s[n] = __builtin_amdgcn_mfma_f32_16x16x32_bf16(qf2[u], kb, s[n], 0, 0, 0);
            }
        __builtin_amdgcn_s_setprio(0);
        if (kt == qt) {   // causal mask only on diagonal tile
            #pragma unroll
            for (int n = 0; n < 4; ++n) {
                int icol = k0 + n * 16 + c;
                #pragma unroll
                for (int j = 0; j < 4; ++j)
                    if (icol > rowt[j]) s[n][j] = -1e30f;
            }
        }
        #pragma unroll
        for (int j = 0; j < 4; ++j) {
            float p0 = exp2f(s[0][j]);
            float p1 = exp2f(s[1][j]);
            float p2 = exp2f(s[2][j]);
            float p3 = exp2f(s[3][j]);
            l_run[j] += (p0 + p1) + (p2 + p3);
            uint2 pk;
            pk.x = f2bf2(p0, p1);
            pk.y = f2bf2(p2, p3);
            *(uint2*)&Ps[wq * 16 + rg * 4 + j][c * 4] = pk;   // ds_write_b64
        }
        __builtin_amdgcn_s_setprio(1);
        #pragma unroll
        for (int u = 0; u < 2; ++u) {
            bf16x8_t pa = *(const bf16x8_t*)&Ps[wq * 16 + fr][u * 32 + fko];
            #pragma unroll
            for (int n = 0; n < 4; ++n) {
                bf16x8_t vb = *(const bf16x8_t*)&Xt[cur][n * 16 + fr][u * 32 + fko];
                acco[n] = __builtin_amdgcn_mfma_f32_16x16x32_bf16(pa, vb, acco[n], 0, 0, 0);
            }
        }
        __builtin_amdgcn_s_setprio(0);
        if (hn) {
            int nxt = cur ^ 1;
            *(bf16x8_t*)&Ks[nxt][si][sdb]     = nk0;
            *(bf16x8_t*)&Ks[nxt][si][sdb + 8] = nk1;
            *(bf16x8_t*)&Xt[nxt][si][sdb]     = nv0;
            *(bf16x8_t*)&Xt[nxt][si][sdb + 8] = nv1;
        }
        __syncthreads();
        cur ^= 1;
    }
    #pragma unroll
    for (int j = 0; j < 4; ++j) {
        l_run[j] += __shfl_xor(l_run[j], 1);
        l_run[j] += __shfl_xor(l_run[j], 2);
        l_run[j] += __shfl_xor(l_run[j], 4);
        l_run[j] += __shfl_xor(l_run[j], 8);
    }
    #pragma unroll
    for (int n = 0; n < 4; ++n) {
        #pragma unroll
        for (int j = 0; j < 4; ++j) {
            float o = acco[n][j] / l_run[j];
            ao[(size_t)rowt[j] * D_DIM + h * HD_DIM + n * 16 + c] = f2bf(o);
        }
    }
}

extern "C" void kernel_launch(void* const* d_in, const int* in_sizes, int n_in,
                              void* d_out, int out_size, void* d_ws, size_t ws_size,
                              hipStream_t stream) {
    const float* x         = (const float*)d_in[0];
    const float* norm1_w   = (const float*)d_in[1];
    const float* norm2_w   = (const float*)d_in[2];
    const float* w_qkv     = (const float*)d_in[3];
    const float* q_norm_w  = (const float*)d_in[4];
    const float* k_norm_w  = (const float*)d_in[5];
    const float* gamma_w1  = (const float*)d_in[6];
    const float* gamma_w2  = (const float*)d_in[7];
    const float* m_persist = (const float*)d_in[8];
    const float* mem_gate  = (const float*)d_in[9];
    const float* w_o       = (const float*)d_in[10];
    const float* ffn_w1    = (const float*)d_in[11];
    const float* ffn_w3    = (const float*)d_in[12];
    const float* ffn_w2    = (const float*)d_in[13];
    float* out = (float*)d_out;
    char* ws = (char*)d_ws;

    const size_t MB = 1024 * 1024;
    u16*   h_bf   = (u16*)(ws);                 // [0,4MB) h / h2
    u16*   wqT    = (u16*)(ws + 4 * MB);        // [4,10)
    u16*   woT    = (u16*)(ws + 10 * MB);       // [10,12)
    u16*   w13T   = (u16*)(ws + 12 * MB);       // [12,23) interleaved w1/w3
    u16*   w2T    = (u16*)(ws + 23 * MB);       // [23,28.5)
    u16*   qkv_bf = (u16*)(ws + 29884416);      // [28.5,40.5) dead after split
    u16*   khT    = (u16*)(ws + 29884416);      // [28.5,32.5) post-split
    u16*   vhT    = (u16*)(ws + 34078720);      // [32.5,36.5)
    u16*   ao_bf  = (u16*)(ws + 38273024);      // [36.5,40.5)
    float* qh     = (float*)(ws + 42467328);    // [40.5,48.5) fp32 q
    u16*   kh     = (u16*)(ws + 50855936);      // [48.5,52.5)
    u16*   vh     = (u16*)(ws + 55050240);      // [52.5,56.5)
    float* gammab = (float*)(ws + 59244544);    // [56.5,+8KB)
    u16*   mid_bf = (u16*)(ws + 29884416);      // [28.5,40) post-attention (11.5MB)

    // residual init for split-K wo GEMM: out = x
    hipMemcpyAsync(out, x, (size_t)S_LEN * D_DIM * sizeof(float),
                   hipMemcpyDeviceToDevice, stream);

    // --- all weight transposes in ONE launch ---------------------------------
    hipLaunchKernelGGL(transpose_all_kernel, dim3(12544), dim3(256), 0, stream,
                       w_qkv, w_o, ffn_w1, ffn_w3, ffn_w2, wqT, woT, w13T, w2T);

    // --- forward pass ---------------------------------------------------------
    hipLaunchKernelGGL(rmsnorm_bf_kernel, dim3(S_LEN), dim3(256), 0, stream,
                       x, norm1_w, h_bf);
    hipLaunchKernelGGL((gemm_bb_kernel<64, 1>), dim3(24, 32), dim3(256), 0, stream,
                       h_bf, wqT, qkv_bf, S_LEN, 3 * D_DIM, D_DIM);
    hipLaunchKernelGGL(split_rope_kernel, dim3(S_LEN / 4, H_NUM), dim3(256), 0, stream,
                       qkv_bf, q_norm_w, k_norm_w, qh, kh, vh);
    hipLaunchKernelGGL(transpose_kv_kernel, dim3(S_LEN / 64, H_NUM), dim3(256), 0, stream,
                       kh, vh, khT, vhT);
    hipLaunchKernelGGL(gamma_kernel, dim3(S_LEN), dim3(256), 0, stream,
                       h_bf, gamma_w1, gamma_w2, gammab);
    hipLaunchKernelGGL(fused_omega_attn_kernel, dim3(512), dim3(256), 0, stream,
                       qh, kh, khT, vhT, gammab, m_persist, mem_gate, ao_bf);
    // x1 = x + ao @ w_o  (out pre-initialized with x; split-K atomic adds)
    hipLaunchKernelGGL(gemm64_splitk_kernel, dim3(16, 32, 2), dim3(256), 0, stream,
                       ao_bf, woT, out, S_LEN, D_DIM, D_DIM, 2);
    hipLaunchKernelGGL(rmsnorm_bf_kernel, dim3(S_LEN), dim3(256), 0, stream,
                       out, norm2_w, h_bf);
    // ffn13 GEMM with fused SwiGLU epilogue -> mid (N=5632 compute, 2816 out)
    hipLaunchKernelGGL((gemm_bb_kernel<64, 2>), dim3(44, 32), dim3(256), 0, stream,
                       h_bf, w13T, mid_bf, S_LEN, 2 * FFNP, D_DIM);
    // out += mid @ w2 (residual = existing out; split-K atomic adds)
    hipLaunchKernelGGL(gemm64_splitk_kernel, dim3(16, 32, 2), dim3(256), 0, stream,
                       mid_bf, w2T, out, S_LEN, D_DIM, FFNP, 2);
}

// Round 14
// 239.977 us; speedup vs baseline: 1.0241x; 1.0241x over previous
//
#include <hip/hip_runtime.h>
#include <hip/hip_bf16.h>

#define S_LEN 2048
#define D_DIM 1024
#define H_NUM 16
#define HD_DIM 64
#define GH_DIM 64
#define FFN_H 2730
#define FFNP  2816          // FFN_H padded to multiple of 128 (zero-filled)
#define CTX_W 512
#define L2LAM -0.00144341687f   // log2(0.999)
#define QBLK 64
#define KBLK 64
#define ALDK 76             // LDS row stride (152B): write-conflict-free, reads <=2-way
#define QSCALE 0.1803368801111731f  // 0.125 * log2(e): scores come out ready for exp2

typedef unsigned short u16;
typedef __attribute__((ext_vector_type(8))) short bf16x8_t;
typedef __attribute__((ext_vector_type(4))) float f32x4_t;

__device__ inline float wave_sum(float v) {
    for (int off = 32; off; off >>= 1) v += __shfl_xor(v, off);
    return v;
}
// f32 -> bf16 (RNE) via the HW pack instruction: 1 VALU op.
__device__ inline u16 f2bf(float f) {
    unsigned r;
    asm("v_cvt_pk_bf16_f32 %0, %1, %2" : "=v"(r) : "v"(f), "v"(f));
    return (u16)r;
}
// pack two f32 -> u32 of 2 bf16 (lo, hi): 1 VALU op.
__device__ inline unsigned f2bf2(float lo, float hi) {
    unsigned r;
    asm("v_cvt_pk_bf16_f32 %0, %1, %2" : "=v"(r) : "v"(lo), "v"(hi));
    return r;
}
__device__ inline float bf2f(u16 u) {
    return __uint_as_float(((unsigned int)u) << 16);
}
__device__ inline void gload16(const void* g, void* l) {
    __builtin_amdgcn_global_load_lds(
        (const __attribute__((address_space(1))) void*)g,
        (__attribute__((address_space(3))) void*)l, 16, 0, 0);
}

// ---------------- RMSNorm (fp32 in -> bf16 out) -----------------------------
__global__ __launch_bounds__(256) void rmsnorm_bf_kernel(const float* __restrict__ in,
    const float* __restrict__ w, u16* __restrict__ out)
{
    int row = blockIdx.x;
    const float4* ir = reinterpret_cast<const float4*>(in + (size_t)row * D_DIM);
    float4 v = ir[threadIdx.x];
    float ss = v.x*v.x + v.y*v.y + v.z*v.z + v.w*v.w;
    ss = wave_sum(ss);
    __shared__ float wsum[4];
    if ((threadIdx.x & 63) == 0) wsum[threadIdx.x >> 6] = ss;
    __syncthreads();
    float tot = wsum[0] + wsum[1] + wsum[2] + wsum[3];
    float scale = rsqrtf(tot / (float)D_DIM + 1e-6f);
    const float4* wr = reinterpret_cast<const float4*>(w);
    float4 wv = wr[threadIdx.x];
    uint2 o;
    o.x = f2bf2(v.x * scale * wv.x, v.y * scale * wv.y);
    o.y = f2bf2(v.z * scale * wv.z, v.w * scale * wv.w);
    *reinterpret_cast<uint2*>(out + (size_t)row * D_DIM + threadIdx.x * 4) = o;
}

// ------------- fused all-weight transpose+convert (5 segments, 1 launch) ----
__global__ __launch_bounds__(256) void transpose_all_kernel(
    const float* __restrict__ w_qkv, const float* __restrict__ w_o,
    const float* __restrict__ w1, const float* __restrict__ w3,
    const float* __restrict__ w2f, u16* __restrict__ wqT,
    u16* __restrict__ woT, u16* __restrict__ w13T, u16* __restrict__ w2T)
{
    __shared__ float tile[32][33];
    int b = blockIdx.x;
    const float* src; u16* dst;
    int srcK, srcN, Kp, rowOff, rowMul, nbx;
    if (b < 3072)      {           src = w_qkv; dst = wqT;  srcK = 1024; srcN = 3072; Kp = 1024; rowOff = 0; rowMul = 1; nbx = 96; }
    else if (b < 4096) { b -= 3072; src = w_o;  dst = woT;  srcK = 1024; srcN = 1024; Kp = 1024; rowOff = 0; rowMul = 1; nbx = 32; }
    else if (b < 6912) { b -= 4096; src = w1;   dst = w13T; srcK = 1024; srcN = 2730; Kp = 1024; rowOff = 0; rowMul = 2; nbx = 88; }
    else if (b < 9728) { b -= 6912; src = w3;   dst = w13T; srcK = 1024; srcN = 2730; Kp = 1024; rowOff = 1; rowMul = 2; nbx = 88; }
    else               { b -= 9728; src = w2f;  dst = w2T;  srcK = 2730; srcN = 1024; Kp = 2816; rowOff = 0; rowMul = 1; nbx = 32; }
    int n0 = (b % nbx) * 32, k0 = (b / nbx) * 32;
    int tx = threadIdx.x & 31, ty = threadIdx.x >> 5;
    #pragma unroll
    for (int p = 0; p < 4; ++p) {
        int kk = ty + p * 8;
        int r = k0 + kk, c = n0 + tx;
        tile[kk][tx] = (r < srcK && c < srcN) ? src[(size_t)r * srcN + c] : 0.f;
    }
    __syncthreads();
    #pragma unroll
    for (int p = 0; p < 4; ++p) {
        int nn = ty + p * 8;
        dst[(size_t)(rowOff + (n0 + nn) * rowMul) * Kp + k0 + tx] = f2bf(tile[tx][nn]);
    }
}

// ---- fused split qkv + qk rmsnorm + RoPE + KV transpose (one launch) -------
// Block = (64-token tile, head). Waves process 16 tokens each (lane = d);
// K/V land in LDS and are written transposed+permuted to khT/vhT. The
// row-major vh buffer is eliminated entirely.
__global__ __launch_bounds__(256) void split_rope_tr_kernel(
    const u16* __restrict__ qkv, const float* __restrict__ qw,
    const float* __restrict__ kw, float* __restrict__ qhp,
    u16* __restrict__ khp, u16* __restrict__ khT, u16* __restrict__ vhT)
{
    __shared__ u16 tk[64][ALDK];
    __shared__ u16 tv[64][ALDK];
    int tid = threadIdx.x;
    int w = tid >> 6, d = tid & 63;
    int h = blockIdx.y;
    int s0 = blockIdx.x * 64;
    float qwv = qw[d], kwv = kw[d];
    int j = d & 31;
    float inv = expf(-(float)j * (9.2103403719761836f / 32.0f));
    float sgn = (d < 32) ? -1.f : 1.f;
    for (int i = 0; i < 16; ++i) {
        int sl = w * 16 + i;
        int s = s0 + sl;
        size_t base = (size_t)s * (3 * D_DIM) + h * HD_DIM + d;
        float qv = bf2f(qkv[base]);
        float kv = bf2f(qkv[base + D_DIM]);
        u16  vv = qkv[base + 2 * D_DIM];
        float sq = wave_sum(qv * qv);
        float qn = qv * rsqrtf(sq / (float)HD_DIM + 1e-6f) * qwv;
        float sk = wave_sum(kv * kv);
        float kn = kv * rsqrtf(sk / (float)HD_DIM + 1e-6f) * kwv;
        float ang = (float)s * inv;
        float cs = cosf(ang), sn = sinf(ang);
        float qp = __shfl_xor(qn, 32);
        float kp = __shfl_xor(kn, 32);
        float qo = qn * cs + sgn * qp * sn;
        float ko = kn * cs + sgn * kp * sn;
        size_t ob = ((size_t)h * S_LEN + s) * HD_DIM + d;
        u16 kb = f2bf(ko);
        qhp[ob] = qo;
        khp[ob] = kb;
        tk[sl][d] = kb;
        tv[sl][d] = vv;
    }
    __syncthreads();
    int r = tid >> 2, cc = (tid & 3) * 16;
    union { u16 u[16]; bf16x8_t v[2]; } ok, ov;
    #pragma unroll
    for (int e = 0; e < 16; ++e) {
        int ksrc = (e & 3) * 16 + (tid & 3) * 4 + (e >> 2);   // pi^-1 permute
        ok.u[e] = tk[ksrc][r]; ov.u[e] = tv[ksrc][r];
    }
    u16* kd = khT + ((size_t)h * HD_DIM + r) * S_LEN + s0 + cc;
    u16* vd = vhT + ((size_t)h * HD_DIM + r) * S_LEN + s0 + cc;
    *(bf16x8_t*)kd       = ok.v[0];
    *(bf16x8_t*)(kd + 8) = ok.v[1];
    *(bf16x8_t*)vd       = ov.v[0];
    *(bf16x8_t*)(vd + 8) = ov.v[1];
}

// ---------------- bf16 MFMA GEMM, 128-col tiles ------------------------------
// MODE 1: bf16 out.  MODE 2: paired silu-mul, bf16 out width N/2.
template<int BM, int MODE>
__global__ __launch_bounds__(256) void gemm_bb_kernel(
    const u16* __restrict__ A, const u16* __restrict__ B,
    u16* __restrict__ Cb, int M, int N, int K)
{
    constexpr int MREP = BM / 32;
    constexpr int ACH  = BM / 32;
    __shared__ u16 As[BM * 64];
    __shared__ u16 Bs[128 * 64];
    int tid = threadIdx.x, lane = tid & 63, wid = tid >> 6;
    int wr = wid >> 1, wc = wid & 1;
    int row0 = blockIdx.y * BM, col0 = blockIdx.x * 128;
    int l8 = lane >> 3, l7 = lane & 7;
    f32x4_t acc[MREP][4];
    #pragma unroll
    for (int i = 0; i < MREP; ++i)
        #pragma unroll
        for (int j = 0; j < 4; ++j) acc[i][j] = (f32x4_t)0.f;

    int fr = lane & 15, fo = (lane >> 4) * 8;
    for (int k0 = 0; k0 < K; k0 += 64) {
        #pragma unroll
        for (int i = 0; i < ACH; ++i) {
            int ch = wid * ACH + i;
            const u16* ga = A + (size_t)(row0 + ch * 8 + l8) * K + k0 + l7 * 8;
            gload16(ga, &As[ch * 512]);
        }
        #pragma unroll
        for (int i = 0; i < 4; ++i) {
            int ch = wid * 4 + i;
            const u16* gb = B + (size_t)(col0 + ch * 8 + l8) * K + k0 + l7 * 8;
            gload16(gb, &Bs[ch * 512]);
        }
        __syncthreads();
        __builtin_amdgcn_s_setprio(1);
        #pragma unroll
        for (int khf = 0; khf < 2; ++khf) {
            bf16x8_t bfrag[4];
            #pragma unroll
            for (int ni = 0; ni < 4; ++ni)
                bfrag[ni] = *(const bf16x8_t*)&Bs[(wc * 64 + ni * 16 + fr) * 64 + khf * 32 + fo];
            #pragma unroll
            for (int mi = 0; mi < MREP; ++mi) {
                bf16x8_t af = *(const bf16x8_t*)&As[(wr * (BM / 2) + mi * 16 + fr) * 64 + khf * 32 + fo];
                #pragma unroll
                for (int ni = 0; ni < 4; ++ni)
                    acc[mi][ni] = __builtin_amdgcn_mfma_f32_16x16x32_bf16(
                        af, bfrag[ni], acc[mi][ni], 0, 0, 0);
            }
        }
        __builtin_amdgcn_s_setprio(0);
        __syncthreads();
    }
    int dr = (lane >> 4) * 4, dc = lane & 15;
    #pragma unroll
    for (int mi = 0; mi < MREP; ++mi) {
        int gr = row0 + wr * (BM / 2) + mi * 16 + dr;
        #pragma unroll
        for (int ni = 0; ni < 4; ++ni) {
            int gc = col0 + wc * 64 + ni * 16 + dc;
            #pragma unroll
            for (int j = 0; j < 4; ++j) {
                float v = acc[mi][ni][j];
                if (MODE == 1) {
                    Cb[(size_t)(gr + j) * N + gc] = f2bf(v);
                } else {
                    float partner = __shfl_xor(v, 1);
                    float a1 = (dc & 1) ? partner : v;
                    float a3 = (dc & 1) ? v : partner;
                    float rr = a1 / (1.f + __expf(-a1)) * a3;
                    if (!(dc & 1))
                        Cb[(size_t)(gr + j) * (N >> 1) + (gc >> 1)] = f2bf(rr);
                }
            }
        }
    }
}

// ---------------- bf16 MFMA GEMM, 64x64 tiles, fp32 out + residual ----------
__global__ __launch_bounds__(256) void gemm64_kernel(
    const u16* __restrict__ A, const u16* __restrict__ B,
    const float* __restrict__ res, float* __restrict__ Cf,
    int M, int N, int K)
{
    __shared__ u16 As[64 * 64];
    __shared__ u16 Bs[64 * 64];
    int tid = threadIdx.x, lane = tid & 63, wid = tid >> 6;
    int wr = wid >> 1, wc = wid & 1;
    int row0 = blockIdx.y * 64, col0 = blockIdx.x * 64;
    int l8 = lane >> 3, l7 = lane & 7;
    f32x4_t acc[2][2];
    #pragma unroll
    for (int i = 0; i < 2; ++i)
        #pragma unroll
        for (int j = 0; j < 2; ++j) acc[i][j] = (f32x4_t)0.f;
    int fr = lane & 15, fo = (lane >> 4) * 8;
    for (int k0 = 0; k0 < K; k0 += 64) {
        #pragma unroll
        for (int i = 0; i < 2; ++i) {
            int ch = wid * 2 + i;
            const u16* ga = A + (size_t)(row0 + ch * 8 + l8) * K + k0 + l7 * 8;
            gload16(ga, &As[ch * 512]);
            const u16* gb = B + (size_t)(col0 + ch * 8 + l8) * K + k0 + l7 * 8;
            gload16(gb, &Bs[ch * 512]);
        }
        __syncthreads();
        __builtin_amdgcn_s_setprio(1);
        #pragma unroll
        for (int khf = 0; khf < 2; ++khf) {
            bf16x8_t bfrag[2];
            #pragma unroll
            for (int ni = 0; ni < 2; ++ni)
                bfrag[ni] = *(const bf16x8_t*)&Bs[(wc * 32 + ni * 16 + fr) * 64 + khf * 32 + fo];
            #pragma unroll
            for (int mi = 0; mi < 2; ++mi) {
                bf16x8_t af = *(const bf16x8_t*)&As[(wr * 32 + mi * 16 + fr) * 64 + khf * 32 + fo];
                #pragma unroll
                for (int ni = 0; ni < 2; ++ni)
                    acc[mi][ni] = __builtin_amdgcn_mfma_f32_16x16x32_bf16(
                        af, bfrag[ni], acc[mi][ni], 0, 0, 0);
            }
        }
        __builtin_amdgcn_s_setprio(0);
        __syncthreads();
    }
    int dr = (lane >> 4) * 4, dc = lane & 15;
    #pragma unroll
    for (int mi = 0; mi < 2; ++mi) {
        int gr = row0 + wr * 32 + mi * 16 + dr;
        #pragma unroll
        for (int ni = 0; ni < 2; ++ni) {
            int gc = col0 + wc * 32 + ni * 16 + dc;
            #pragma unroll
            for (int j = 0; j < 4; ++j) {
                size_t off = (size_t)(gr + j) * N + gc;
                Cf[off] = acc[mi][ni][j] + res[off];
            }
        }
    }
}

// ------------- gamma gate (4-wave parallel, 1 token/block) ------------------
__global__ __launch_bounds__(256) void gamma_kernel(const u16* __restrict__ h,
    const float* __restrict__ w1, const float* __restrict__ w2,
    float* __restrict__ gamma)
{
    __shared__ float hl[D_DIM];
    __shared__ float part[4][GH_DIM];
    int s = blockIdx.x, tid = threadIdx.x, lane = tid & 63, w = tid >> 6;
    {
        ushort4 v = *(const ushort4*)(h + (size_t)s * D_DIM + tid * 4);
        hl[tid*4+0] = bf2f(v.x); hl[tid*4+1] = bf2f(v.y);
        hl[tid*4+2] = bf2f(v.z); hl[tid*4+3] = bf2f(v.w);
    }
    __syncthreads();
    float acc = 0.f;
    #pragma unroll 8
    for (int k = w * 256; k < w * 256 + 256; ++k)
        acc += hl[k] * w1[k * GH_DIM + lane];
    part[w][lane] = acc;
    __syncthreads();
    if (w == 0) {
        float tot = part[0][lane] + part[1][lane] + part[2][lane] + part[3][lane];
        float z = tot / (1.f + __expf(-tot));
        float y = z * w2[lane];
        float t2 = wave_sum(y);
        if (lane == 0) gamma[s] = 1.f / (1.f + __expf(-t2));
    }
}

// ============ FUSED omega-rule + flash attention ============================
// 1-D grid, XCD head-locality AND complementary qt pairing:
//   hi = bit8, h = (b&7)*2 + hi, qt = hi ? 31-s5 : s5.
// 1-tile double-buffered loops, no-max softmax, b64 P-stores via cvt_pk and
// the s-column permutation pi(s)=(s&15)*4+(s>>4) pre-applied to khT/vhT.
__global__ __launch_bounds__(256) void fused_omega_attn_kernel(
    const float* __restrict__ qhp, const u16* __restrict__ khp,
    const u16* __restrict__ khT, const u16* __restrict__ vhT,
    const float* __restrict__ gammab, const float* __restrict__ mp,
    const float* __restrict__ mg, u16* __restrict__ ao)
{
    __shared__ u16 Ks[2][KBLK][ALDK];
    __shared__ u16 Xt[2][KBLK][ALDK];
    __shared__ u16 Ps[QBLK][ALDK];
    const int tid = threadIdx.x, lane = tid & 63, wq = tid >> 6;
    const int b = blockIdx.x;
    const int hi = (b >> 8) & 1;
    const int h = ((b & 7) << 1) + hi;
    const int s5 = (b >> 3) & 31;
    const int qt = hi ? (31 - s5) : s5;
    const int q0 = qt * QBLK;
    const int fr = lane & 15, g4 = lane >> 4;
    const int fko = g4 * 8;
    const int c = fr, rg = g4;
    const int si = tid >> 2, sdb = (tid & 3) * 16;
    const size_t hS = (size_t)h * S_LEN;
    const size_t hD = (size_t)h * HD_DIM;

    int rowt[4]; float rowf[4];
    #pragma unroll
    for (int j = 0; j < 4; ++j) {
        rowt[j] = q0 + wq * 16 + rg * 4 + j;
        rowf[j] = exp2f((float)(wq * 16 + rg * 4 + j) * L2LAM);
    }
    // q_old A-fragments (bf16)
    bf16x8_t qf[2];
    {
        const float* qrow = qhp + (hS + q0 + wq * 16 + fr) * HD_DIM;
        #pragma unroll
        for (int u = 0; u < 2; ++u) {
            float4 a = *(const float4*)(qrow + u * 32 + fko);
            float4 bq = *(const float4*)(qrow + u * 32 + fko + 4);
            bf16x8_t f;
            f[0]=f2bf(a.x); f[1]=f2bf(a.y); f[2]=f2bf(a.z); f[3]=f2bf(a.w);
            f[4]=f2bf(bq.x); f[5]=f2bf(bq.y); f[6]=f2bf(bq.z); f[7]=f2bf(bq.w);
            qf[u] = f;
        }
    }
    // ---------------- omega phase (double-buffered) ----------------
    f32x4_t accc[4];
    #pragma unroll
    for (int n = 0; n < 4; ++n) accc[n] = (f32x4_t)0.f;
    float wsum[4] = {0.f, 0.f, 0.f, 0.f};
    const int kt0 = (q0 > (CTX_W - 1)) ? (q0 - (CTX_W - 1)) / KBLK : 0;
    {
        const u16* gk = khp + (hS + kt0 * KBLK + si) * HD_DIM + sdb;
        const u16* gx = khT + (hD + si) * S_LEN + kt0 * KBLK + sdb;
        *(bf16x8_t*)&Ks[0][si][sdb]     = *(const bf16x8_t*)gk;
        *(bf16x8_t*)&Ks[0][si][sdb + 8] = *(const bf16x8_t*)(gk + 8);
        *(bf16x8_t*)&Xt[0][si][sdb]     = *(const bf16x8_t*)gx;
        *(bf16x8_t*)&Xt[0][si][sdb + 8] = *(const bf16x8_t*)(gx + 8);
    }
    __syncthreads();
    int cur = 0;
    for (int kt = kt0; kt <= qt; ++kt) {
        const int k0 = kt * KBLK;
        const bool hn = (kt < qt);
        bf16x8_t nk0, nk1, nx0, nx1;
        if (hn) {
            const u16* gk = khp + (hS + k0 + KBLK + si) * HD_DIM + sdb;
            const u16* gx = khT + (hD + si) * S_LEN + k0 + KBLK + sdb;
            nk0 = *(const bf16x8_t*)gk; nk1 = *(const bf16x8_t*)(gk + 8);
            nx0 = *(const bf16x8_t*)gx; nx1 = *(const bf16x8_t*)(gx + 8);
        }
        f32x4_t s[4];
        #pragma unroll
        for (int n = 0; n < 4; ++n) s[n] = (f32x4_t)0.f;
        __builtin_amdgcn_s_setprio(1);
        #pragma unroll
        for (int u = 0; u < 2; ++u)
            #pragma unroll
            for (int n = 0; n < 4; ++n) {
                bf16x8_t kb = *(const bf16x8_t*)&Ks[cur][n * 16 + fr][u * 32 + fko];
                s[n] = __builtin_amdgcn_mfma_f32_16x16x32_bf16(qf[u], kb, s[n], 0, 0, 0);
            }
        __builtin_amdgcn_s_setprio(0);
        const bool boundary = (kt == kt0) || (kt == qt);
        float colf[4];
        #pragma unroll
        for (int n = 0; n < 4; ++n) {
            int icol = k0 + n * 16 + c;
            colf[n] = exp2f((float)(q0 - icol) * L2LAM) * gammab[icol];
        }
        #pragma unroll
        for (int j = 0; j < 4; ++j) {
            float pv[4];
            #pragma unroll
            for (int n = 0; n < 4; ++n) {
                float w;
                if (boundary) {
                    int delta = rowt[j] - (k0 + n * 16 + c);
                    w = (delta >= 0 && delta < CTX_W) ? rowf[j] * colf[n] : 0.f;
                } else {
                    w = rowf[j] * colf[n];
                }
                wsum[j] += w;
                pv[n] = w * s[n][j];
            }
            uint2 pk;
            pk.x = f2bf2(pv[0], pv[1]);
            pk.y = f2bf2(pv[2], pv[3]);
            *(uint2*)&Ps[wq * 16 + rg * 4 + j][c * 4] = pk;   // ds_write_b64
        }
        __builtin_amdgcn_s_setprio(1);
        #pragma unroll
        for (int u = 0; u < 2; ++u) {
            bf16x8_t pa = *(const bf16x8_t*)&Ps[wq * 16 + fr][u * 32 + fko];
            #pragma unroll
            for (int n = 0; n < 4; ++n) {
                bf16x8_t kb = *(const bf16x8_t*)&Xt[cur][n * 16 + fr][u * 32 + fko];
                accc[n] = __builtin_amdgcn_mfma_f32_16x16x32_bf16(pa, kb, accc[n], 0, 0, 0);
            }
        }
        __builtin_amdgcn_s_setprio(0);
        if (hn) {
            int nxt = cur ^ 1;
            *(bf16x8_t*)&Ks[nxt][si][sdb]     = nk0;
            *(bf16x8_t*)&Ks[nxt][si][sdb + 8] = nk1;
            *(bf16x8_t*)&Xt[nxt][si][sdb]     = nx0;
            *(bf16x8_t*)&Xt[nxt][si][sdb + 8] = nx1;
        }
        __syncthreads();
        cur ^= 1;
    }
    // persist = Q @ M_p^T
    f32x4_t pacc[4];
    #pragma unroll
    for (int n = 0; n < 4; ++n) pacc[n] = (f32x4_t)0.f;
    const float* mph = mp + hD * HD_DIM;
    #pragma unroll
    for (int u = 0; u < 2; ++u)
        #pragma unroll
        for (int n = 0; n < 4; ++n) {
            const float* br = mph + (size_t)(n * 16 + fr) * HD_DIM + u * 32 + fko;
            float4 a = *(const float4*)br;
            float4 bq = *(const float4*)(br + 4);
            bf16x8_t f;
            f[0]=f2bf(a.x); f[1]=f2bf(a.y); f[2]=f2bf(a.z); f[3]=f2bf(a.w);
            f[4]=f2bf(bq.x); f[5]=f2bf(bq.y); f[6]=f2bf(bq.z); f[7]=f2bf(bq.w);
            pacc[n] = __builtin_amdgcn_mfma_f32_16x16x32_bf16(qf[u], f, pacc[n], 0, 0, 0);
        }
    #pragma unroll
    for (int j = 0; j < 4; ++j) {
        wsum[j] += __shfl_xor(wsum[j], 1);
        wsum[j] += __shfl_xor(wsum[j], 2);
        wsum[j] += __shfl_xor(wsum[j], 4);
        wsum[j] += __shfl_xor(wsum[j], 8);
    }
    float gate = 1.f / (1.f + __expf(-mg[0]));
    float keep = 1.f - gate;
    // q_new (pre-scaled by 0.125*log2e) -> wave-private rows (d-domain, scalar)
    #pragma unroll
    for (int n = 0; n < 4; ++n) {
        #pragma unroll
        for (int j = 0; j < 4; ++j) {
            float qold = qhp[(hS + rowt[j]) * HD_DIM + n * 16 + c];
            float qn = keep * qold + gate * (pacc[n][j] + accc[n][j]) / (1.f + wsum[j]);
            Ps[wq * 16 + rg * 4 + j][n * 16 + c] = f2bf(qn * QSCALE);
        }
    }
    bf16x8_t qf2[2];
    #pragma unroll
    for (int u = 0; u < 2; ++u)
        qf2[u] = *(const bf16x8_t*)&Ps[wq * 16 + fr][u * 32 + fko];

    // ---------------- attention phase (double-buffered, no-max softmax) -----
    f32x4_t acco[4];
    #pragma unroll
    for (int n = 0; n < 4; ++n) acco[n] = (f32x4_t)0.f;
    float l_run[4] = {0.f, 0.f, 0.f, 0.f};
    {   // prologue: stage tile 0 into buffer 0 (all omega reads done)
        const u16* gk = khp + (hS + si) * HD_DIM + sdb;
        const u16* gv = vhT + (hD + si) * S_LEN + sdb;
        *(bf16x8_t*)&Ks[0][si][sdb]     = *(const bf16x8_t*)gk;
        *(bf16x8_t*)&Ks[0][si][sdb + 8] = *(const bf16x8_t*)(gk + 8);
        *(bf16x8_t*)&Xt[0][si][sdb]     = *(const bf16x8_t*)gv;
        *(bf16x8_t*)&Xt[0][si][sdb + 8] = *(const bf16x8_t*)(gv + 8);
    }
    __syncthreads();
    cur = 0;
    for (int kt = 0; kt <= qt; ++kt) {
        const int k0 = kt * KBLK;
        const bool hn = (kt < qt);
        bf16x8_t nk0, nk1, nv0, nv1;
        if (hn) {
            const u16* gk = khp + (hS + k0 + KBLK + si) * HD_DIM + sdb;
            const u16* gv = vhT + (hD + si) * S_LEN + k0 + KBLK + sdb;
            nk0 = *(const bf16x8_t*)gk; nk1 = *(const bf16x8_t*)(gk + 8);
            nv0 = *(const bf16x8_t*)gv; nv1 = *(const bf16x8_t*)(gv + 8);
        }
        f32x4_t s[4];
        #pragma unroll
        for (int n = 0; n < 4; ++n) s[n] = (f32x4_t)0.f;
        __builtin_amdgcn_s_setprio(1);
        #pragma unroll
        for (int u = 0; u < 2; ++u)
            #pragma unroll
            for (int n = 0; n < 4; ++n) {
                bf16x8_t kb = *(const bf16x8_t*)&Ks[cur][n * 16 + fr][u * 32 + fko];
                s[n] = __builtin_amdgcn_mfma_f32_16x16x32_bf16(qf2[u], kb, s[n], 0, 0, 0);
            }
        __builtin_amdgcn_s_setprio(0);
        if (kt == qt) {   // causal mask only on diagonal tile
            #pragma unroll
            for (int n = 0; n < 4; ++n) {
                int icol = k0 + n * 16 + c;
                #pragma unroll
                for (int j = 0; j < 4; ++j)
                    if (icol > rowt[j]) s[n][j] = -1e30f;
            }
        }
        #pragma unroll
        for (int j = 0; j < 4; ++j) {
            float p0 = exp2f(s[0][j]);
            float p1 = exp2f(s[1][j]);
            float p2 = exp2f(s[2][j]);
            float p3 = exp2f(s[3][j]);
            l_run[j] += (p0 + p1) + (p2 + p3);
            uint2 pk;
            pk.x = f2bf2(p0, p1);
            pk.y = f2bf2(p2, p3);
            *(uint2*)&Ps[wq * 16 + rg * 4 + j][c * 4] = pk;   // ds_write_b64
        }
        __builtin_amdgcn_s_setprio(1);
        #pragma unroll
        for (int u = 0; u < 2; ++u) {
            bf16x8_t pa = *(const bf16x8_t*)&Ps[wq * 16 + fr][u * 32 + fko];
            #pragma unroll
            for (int n = 0; n < 4; ++n) {
                bf16x8_t vb = *(const bf16x8_t*)&Xt[cur][n * 16 + fr][u * 32 + fko];
                acco[n] = __builtin_amdgcn_mfma_f32_16x16x32_bf16(pa, vb, acco[n], 0, 0, 0);
            }
        }
        __builtin_amdgcn_s_setprio(0);
        if (hn) {
            int nxt = cur ^ 1;
            *(bf16x8_t*)&Ks[nxt][si][sdb]     = nk0;
            *(bf16x8_t*)&Ks[nxt][si][sdb + 8] = nk1;
            *(bf16x8_t*)&Xt[nxt][si][sdb]     = nv0;
            *(bf16x8_t*)&Xt[nxt][si][sdb + 8] = nv1;
        }
        __syncthreads();
        cur ^= 1;
    }
    #pragma unroll
    for (int j = 0; j < 4; ++j) {
        l_run[j] += __shfl_xor(l_run[j], 1);
        l_run[j] += __shfl_xor(l_run[j], 2);
        l_run[j] += __shfl_xor(l_run[j], 4);
        l_run[j] += __shfl_xor(l_run[j], 8);
    }
    #pragma unroll
    for (int n = 0; n < 4; ++n) {
        #pragma unroll
        for (int j = 0; j < 4; ++j) {
            float o = acco[n][j] / l_run[j];
            ao[(size_t)rowt[j] * D_DIM + h * HD_DIM + n * 16 + c] = f2bf(o);
        }
    }
}

extern "C" void kernel_launch(void* const* d_in, const int* in_sizes, int n_in,
                              void* d_out, int out_size, void* d_ws, size_t ws_size,
                              hipStream_t stream) {
    const float* x         = (const float*)d_in[0];
    const float* norm1_w   = (const float*)d_in[1];
    const float* norm2_w   = (const float*)d_in[2];
    const float* w_qkv     = (const float*)d_in[3];
    const float* q_norm_w  = (const float*)d_in[4];
    const float* k_norm_w  = (const float*)d_in[5];
    const float* gamma_w1  = (const float*)d_in[6];
    const float* gamma_w2  = (const float*)d_in[7];
    const float* m_persist = (const float*)d_in[8];
    const float* mem_gate  = (const float*)d_in[9];
    const float* w_o       = (const float*)d_in[10];
    const float* ffn_w1    = (const float*)d_in[11];
    const float* ffn_w3    = (const float*)d_in[12];
    const float* ffn_w2    = (const float*)d_in[13];
    float* out = (float*)d_out;
    char* ws = (char*)d_ws;

    const size_t MB = 1024 * 1024;
    u16*   h_bf   = (u16*)(ws);                 // [0,4MB) h / h2
    u16*   wqT    = (u16*)(ws + 4 * MB);        // [4,10)
    u16*   woT    = (u16*)(ws + 10 * MB);       // [10,12)
    u16*   w13T   = (u16*)(ws + 12 * MB);       // [12,23) interleaved w1/w3
    u16*   w2T    = (u16*)(ws + 23 * MB);       // [23,28.5)
    u16*   qkv_bf = (u16*)(ws + 29884416);      // [28.5,40.5) dead after split
    u16*   khT    = (u16*)(ws + 29884416);      // [28.5,32.5) post-split
    u16*   vhT    = (u16*)(ws + 34078720);      // [32.5,36.5)
    u16*   ao_bf  = (u16*)(ws + 38273024);      // [36.5,40.5)
    float* qh     = (float*)(ws + 42467328);    // [40.5,48.5) fp32 q
    u16*   kh     = (u16*)(ws + 50855936);      // [48.5,52.5)
    float* gammab = (float*)(ws + 59244544);    // [56.5,+8KB)
    u16*   mid_bf = (u16*)(ws + 29884416);      // [28.5,40) post-attention (11.5MB)

    // --- all weight transposes in ONE launch ---------------------------------
    hipLaunchKernelGGL(transpose_all_kernel, dim3(12544), dim3(256), 0, stream,
                       w_qkv, w_o, ffn_w1, ffn_w3, ffn_w2, wqT, woT, w13T, w2T);

    // --- forward pass ---------------------------------------------------------
    hipLaunchKernelGGL(rmsnorm_bf_kernel, dim3(S_LEN), dim3(256), 0, stream,
                       x, norm1_w, h_bf);
    hipLaunchKernelGGL((gemm_bb_kernel<64, 1>), dim3(24, 32), dim3(256), 0, stream,
                       h_bf, wqT, qkv_bf, S_LEN, 3 * D_DIM, D_DIM);
    // NOTE: split_rope_tr writes khT into the qkv_bf region while still
    // reading qkv_bf -- but khT [28.5,32.5) overlaps qkv columns it reads!
    // Avoid aliasing: khT/vhT writes happen after all qkv reads of the same
    // block, but OTHER blocks still read qkv. So khT/vhT must NOT alias
    // qkv_bf. Place khT/vhT in the free region [48.5,56.5) instead.
    {
        u16* khT2 = (u16*)(ws + 50855936 + 4 * MB);   // [52.5,56.5) unused now
        // kh occupies [48.5,52.5); khT2 at [52.5,56.5); vhT needs 4MB more ->
        // use [23,28.5) after... w2T still live. Use ao region? ao written later.
        // Simplest safe placement: vhT at [36.5,40.5) (ao region) is written by
        // split BEFORE ao exists; ao is written by fused kernel AFTER vhT's last
        // read? NO - fused reads vhT while writing ao. Keep vhT at its own spot:
        // move khT to [52.5,56.5) and vhT stays at [32.5,36.5) which aliases
        // qkv_bf!  -> allocate vhT at [56.5,60.5) instead (gammab moves to tail).
        (void)khT2;
    }
    u16* khT_s = (u16*)(ws + 50855936 + 4 * MB);   // [52.5,56.5)
    u16* vhT_s = (u16*)(ws + 59244544 + 64 * 1024); // [56.5+64KB, +4MB)
    hipLaunchKernelGGL(split_rope_tr_kernel, dim3(S_LEN / 64, H_NUM), dim3(256), 0, stream,
                       qkv_bf, q_norm_w, k_norm_w, qh, kh, khT_s, vhT_s);
    hipLaunchKernelGGL(gamma_kernel, dim3(S_LEN), dim3(256), 0, stream,
                       h_bf, gamma_w1, gamma_w2, gammab);
    hipLaunchKernelGGL(fused_omega_attn_kernel, dim3(512), dim3(256), 0, stream,
                       qh, kh, khT_s, vhT_s, gammab, m_persist, mem_gate, ao_bf);
    hipLaunchKernelGGL(gemm64_kernel, dim3(16, 32), dim3(256), 0, stream,
                       ao_bf, woT, x, out, S_LEN, D_DIM, D_DIM);
    hipLaunchKernelGGL(rmsnorm_bf_kernel, dim3(S_LEN), dim3(256), 0, stream,
                       out, norm2_w, h_bf);
    // ffn13 GEMM with fused SwiGLU epilogue -> mid (N=5632 compute, 2816 out)
    hipLaunchKernelGGL((gemm_bb_kernel<64, 2>), dim3(44, 32), dim3(256), 0, stream,
                       h_bf, w13T, mid_bf, S_LEN, 2 * FFNP, D_DIM);
    hipLaunchKernelGGL(gemm64_kernel, dim3(16, 32), dim3(256), 0, stream,
                       mid_bf, w2T, out, out, S_LEN, D_DIM, FFNP);
}

// Round 15
// 235.152 us; speedup vs baseline: 1.0451x; 1.0205x over previous
//
#include <hip/hip_runtime.h>
#include <hip/hip_bf16.h>

#define S_LEN 2048
#define D_DIM 1024
#define H_NUM 16
#define HD_DIM 64
#define GH_DIM 64
#define FFN_H 2730
#define FFNP  2816          // FFN_H padded to multiple of 128 (zero-filled)
#define CTX_W 512
#define L2LAM -0.00144341687f   // log2(0.999)
#define QBLK 64
#define KBLK 64
#define ALDK 76             // LDS row stride (152B): write-conflict-free, reads <=2-way
#define QSCALE 0.1803368801111731f  // 0.125 * log2(e): scores come out ready for exp2

typedef unsigned short u16;
typedef __attribute__((ext_vector_type(8))) short bf16x8_t;
typedef __attribute__((ext_vector_type(4))) float f32x4_t;

__device__ inline float wave_sum(float v) {
    for (int off = 32; off; off >>= 1) v += __shfl_xor(v, off);
    return v;
}
// f32 -> bf16 (RNE) via the HW pack instruction: 1 VALU op.
__device__ inline u16 f2bf(float f) {
    unsigned r;
    asm("v_cvt_pk_bf16_f32 %0, %1, %2" : "=v"(r) : "v"(f), "v"(f));
    return (u16)r;
}
// pack two f32 -> u32 of 2 bf16 (lo, hi): 1 VALU op.
__device__ inline unsigned f2bf2(float lo, float hi) {
    unsigned r;
    asm("v_cvt_pk_bf16_f32 %0, %1, %2" : "=v"(r) : "v"(lo), "v"(hi));
    return r;
}
__device__ inline float bf2f(u16 u) {
    return __uint_as_float(((unsigned int)u) << 16);
}
__device__ inline void gload16(const void* g, void* l) {
    __builtin_amdgcn_global_load_lds(
        (const __attribute__((address_space(1))) void*)g,
        (__attribute__((address_space(3))) void*)l, 16, 0, 0);
}

// ------- RMSNorm (fp32 in -> bf16 out), optionally fused gamma gate ---------
template<bool GAMMA>
__global__ __launch_bounds__(256) void rmsnorm_gamma_kernel(
    const float* __restrict__ in, const float* __restrict__ w,
    u16* __restrict__ out, const float* __restrict__ w1,
    const float* __restrict__ w2, float* __restrict__ gamma)
{
    __shared__ float hl[D_DIM];
    __shared__ float part[4][GH_DIM];
    int row = blockIdx.x;
    int tid = threadIdx.x, lane = tid & 63, wv = tid >> 6;
    const float4* ir = reinterpret_cast<const float4*>(in + (size_t)row * D_DIM);
    float4 v = ir[tid];
    float ss = v.x*v.x + v.y*v.y + v.z*v.z + v.w*v.w;
    ss = wave_sum(ss);
    __shared__ float wsum[4];
    if (lane == 0) wsum[wv] = ss;
    __syncthreads();
    float tot = wsum[0] + wsum[1] + wsum[2] + wsum[3];
    float scale = rsqrtf(tot / (float)D_DIM + 1e-6f);
    const float4* wr = reinterpret_cast<const float4*>(w);
    float4 wv4 = wr[tid];
    float h0 = v.x * scale * wv4.x, h1 = v.y * scale * wv4.y;
    float h2 = v.z * scale * wv4.z, h3 = v.w * scale * wv4.w;
    uint2 o;
    o.x = f2bf2(h0, h1);
    o.y = f2bf2(h2, h3);
    *reinterpret_cast<uint2*>(out + (size_t)row * D_DIM + tid * 4) = o;
    if (GAMMA) {
        hl[tid*4+0] = h0; hl[tid*4+1] = h1; hl[tid*4+2] = h2; hl[tid*4+3] = h3;
        __syncthreads();
        float acc = 0.f;
        #pragma unroll 8
        for (int k = wv * 256; k < wv * 256 + 256; ++k)
            acc += hl[k] * w1[k * GH_DIM + lane];
        part[wv][lane] = acc;
        __syncthreads();
        if (wv == 0) {
            float t = part[0][lane] + part[1][lane] + part[2][lane] + part[3][lane];
            float z = t / (1.f + __expf(-t));
            float y = z * w2[lane];
            float t2 = wave_sum(y);
            if (lane == 0) gamma[row] = 1.f / (1.f + __expf(-t2));
        }
    }
}

// ------------- fused all-weight transpose+convert (5 segments, 1 launch) ----
__global__ __launch_bounds__(256) void transpose_all_kernel(
    const float* __restrict__ w_qkv, const float* __restrict__ w_o,
    const float* __restrict__ w1, const float* __restrict__ w3,
    const float* __restrict__ w2f, u16* __restrict__ wqT,
    u16* __restrict__ woT, u16* __restrict__ w13T, u16* __restrict__ w2T)
{
    __shared__ float tile[32][33];
    int b = blockIdx.x;
    const float* src; u16* dst;
    int srcK, srcN, Kp, rowOff, rowMul, nbx;
    if (b < 3072)      {           src = w_qkv; dst = wqT;  srcK = 1024; srcN = 3072; Kp = 1024; rowOff = 0; rowMul = 1; nbx = 96; }
    else if (b < 4096) { b -= 3072; src = w_o;  dst = woT;  srcK = 1024; srcN = 1024; Kp = 1024; rowOff = 0; rowMul = 1; nbx = 32; }
    else if (b < 6912) { b -= 4096; src = w1;   dst = w13T; srcK = 1024; srcN = 2730; Kp = 1024; rowOff = 0; rowMul = 2; nbx = 88; }
    else if (b < 9728) { b -= 6912; src = w3;   dst = w13T; srcK = 1024; srcN = 2730; Kp = 1024; rowOff = 1; rowMul = 2; nbx = 88; }
    else               { b -= 9728; src = w2f;  dst = w2T;  srcK = 2730; srcN = 1024; Kp = 2816; rowOff = 0; rowMul = 1; nbx = 32; }
    int n0 = (b % nbx) * 32, k0 = (b / nbx) * 32;
    int tx = threadIdx.x & 31, ty = threadIdx.x >> 5;
    #pragma unroll
    for (int p = 0; p < 4; ++p) {
        int kk = ty + p * 8;
        int r = k0 + kk, c = n0 + tx;
        tile[kk][tx] = (r < srcK && c < srcN) ? src[(size_t)r * srcN + c] : 0.f;
    }
    __syncthreads();
    #pragma unroll
    for (int p = 0; p < 4; ++p) {
        int nn = ty + p * 8;
        dst[(size_t)(rowOff + (n0 + nn) * rowMul) * Kp + k0 + tx] = f2bf(tile[tx][nn]);
    }
}

// ---- fused split qkv + qk rmsnorm + RoPE + KV transpose (one launch) -------
__global__ __launch_bounds__(256) void split_rope_tr_kernel(
    const u16* __restrict__ qkv, const float* __restrict__ qw,
    const float* __restrict__ kw, float* __restrict__ qhp,
    u16* __restrict__ khp, u16* __restrict__ khT, u16* __restrict__ vhT)
{
    __shared__ u16 tk[64][ALDK];
    __shared__ u16 tv[64][ALDK];
    int tid = threadIdx.x;
    int w = tid >> 6, d = tid & 63;
    int h = blockIdx.y;
    int s0 = blockIdx.x * 64;
    float qwv = qw[d], kwv = kw[d];
    int j = d & 31;
    float inv = expf(-(float)j * (9.2103403719761836f / 32.0f));
    float sgn = (d < 32) ? -1.f : 1.f;
    for (int i = 0; i < 16; ++i) {
        int sl = w * 16 + i;
        int s = s0 + sl;
        size_t base = (size_t)s * (3 * D_DIM) + h * HD_DIM + d;
        float qv = bf2f(qkv[base]);
        float kv = bf2f(qkv[base + D_DIM]);
        u16  vv = qkv[base + 2 * D_DIM];
        float sq = wave_sum(qv * qv);
        float qn = qv * rsqrtf(sq / (float)HD_DIM + 1e-6f) * qwv;
        float sk = wave_sum(kv * kv);
        float kn = kv * rsqrtf(sk / (float)HD_DIM + 1e-6f) * kwv;
        float ang = (float)s * inv;
        float cs = cosf(ang), sn = sinf(ang);
        float qp = __shfl_xor(qn, 32);
        float kp = __shfl_xor(kn, 32);
        float qo = qn * cs + sgn * qp * sn;
        float ko = kn * cs + sgn * kp * sn;
        size_t ob = ((size_t)h * S_LEN + s) * HD_DIM + d;
        u16 kb = f2bf(ko);
        qhp[ob] = qo;
        khp[ob] = kb;
        tk[sl][d] = kb;
        tv[sl][d] = vv;
    }
    __syncthreads();
    int r = tid >> 2, cc = (tid & 3) * 16;
    union { u16 u[16]; bf16x8_t v[2]; } ok, ov;
    #pragma unroll
    for (int e = 0; e < 16; ++e) {
        int ksrc = (e & 3) * 16 + (tid & 3) * 4 + (e >> 2);   // pi^-1 permute
        ok.u[e] = tk[ksrc][r]; ov.u[e] = tv[ksrc][r];
    }
    u16* kd = khT + ((size_t)h * HD_DIM + r) * S_LEN + s0 + cc;
    u16* vd = vhT + ((size_t)h * HD_DIM + r) * S_LEN + s0 + cc;
    *(bf16x8_t*)kd       = ok.v[0];
    *(bf16x8_t*)(kd + 8) = ok.v[1];
    *(bf16x8_t*)vd       = ov.v[0];
    *(bf16x8_t*)(vd + 8) = ov.v[1];
}

// ---------------- bf16 MFMA GEMM, 128-col tiles ------------------------------
// MODE 1: bf16 out.  MODE 2: paired silu-mul, bf16 out width N/2.
template<int BM, int MODE>
__global__ __launch_bounds__(256) void gemm_bb_kernel(
    const u16* __restrict__ A, const u16* __restrict__ B,
    u16* __restrict__ Cb, int M, int N, int K)
{
    constexpr int MREP = BM / 32;
    constexpr int ACH  = BM / 32;
    __shared__ u16 As[BM * 64];
    __shared__ u16 Bs[128 * 64];
    int tid = threadIdx.x, lane = tid & 63, wid = tid >> 6;
    int wr = wid >> 1, wc = wid & 1;
    int row0 = blockIdx.y * BM, col0 = blockIdx.x * 128;
    int l8 = lane >> 3, l7 = lane & 7;
    f32x4_t acc[MREP][4];
    #pragma unroll
    for (int i = 0; i < MREP; ++i)
        #pragma unroll
        for (int j = 0; j < 4; ++j) acc[i][j] = (f32x4_t)0.f;

    int fr = lane & 15, fo = (lane >> 4) * 8;
    for (int k0 = 0; k0 < K; k0 += 64) {
        #pragma unroll
        for (int i = 0; i < ACH; ++i) {
            int ch = wid * ACH + i;
            const u16* ga = A + (size_t)(row0 + ch * 8 + l8) * K + k0 + l7 * 8;
            gload16(ga, &As[ch * 512]);
        }
        #pragma unroll
        for (int i = 0; i < 4; ++i) {
            int ch = wid * 4 + i;
            const u16* gb = B + (size_t)(col0 + ch * 8 + l8) * K + k0 + l7 * 8;
            gload16(gb, &Bs[ch * 512]);
        }
        __syncthreads();
        __builtin_amdgcn_s_setprio(1);
        #pragma unroll
        for (int khf = 0; khf < 2; ++khf) {
            bf16x8_t bfrag[4];
            #pragma unroll
            for (int ni = 0; ni < 4; ++ni)
                bfrag[ni] = *(const bf16x8_t*)&Bs[(wc * 64 + ni * 16 + fr) * 64 + khf * 32 + fo];
            #pragma unroll
            for (int mi = 0; mi < MREP; ++mi) {
                bf16x8_t af = *(const bf16x8_t*)&As[(wr * (BM / 2) + mi * 16 + fr) * 64 + khf * 32 + fo];
                #pragma unroll
                for (int ni = 0; ni < 4; ++ni)
                    acc[mi][ni] = __builtin_amdgcn_mfma_f32_16x16x32_bf16(
                        af, bfrag[ni], acc[mi][ni], 0, 0, 0);
            }
        }
        __builtin_amdgcn_s_setprio(0);
        __syncthreads();
    }
    int dr = (lane >> 4) * 4, dc = lane & 15;
    #pragma unroll
    for (int mi = 0; mi < MREP; ++mi) {
        int gr = row0 + wr * (BM / 2) + mi * 16 + dr;
        #pragma unroll
        for (int ni = 0; ni < 4; ++ni) {
            int gc = col0 + wc * 64 + ni * 16 + dc;
            #pragma unroll
            for (int j = 0; j < 4; ++j) {
                float v = acc[mi][ni][j];
                if (MODE == 1) {
                    Cb[(size_t)(gr + j) * N + gc] = f2bf(v);
                } else {
                    float partner = __shfl_xor(v, 1);
                    float a1 = (dc & 1) ? partner : v;
                    float a3 = (dc & 1) ? v : partner;
                    float rr = a1 / (1.f + __expf(-a1)) * a3;
                    if (!(dc & 1))
                        Cb[(size_t)(gr + j) * (N >> 1) + (gc >> 1)] = f2bf(rr);
                }
            }
        }
    }
}

// ---------------- bf16 MFMA GEMM, 64x64 tiles, fp32 out + residual ----------
__global__ __launch_bounds__(256) void gemm64_kernel(
    const u16* __restrict__ A, const u16* __restrict__ B,
    const float* __restrict__ res, float* __restrict__ Cf,
    int M, int N, int K)
{
    __shared__ u16 As[64 * 64];
    __shared__ u16 Bs[64 * 64];
    int tid = threadIdx.x, lane = tid & 63, wid = tid >> 6;
    int wr = wid >> 1, wc = wid & 1;
    int row0 = blockIdx.y * 64, col0 = blockIdx.x * 64;
    int l8 = lane >> 3, l7 = lane & 7;
    f32x4_t acc[2][2];
    #pragma unroll
    for (int i = 0; i < 2; ++i)
        #pragma unroll
        for (int j = 0; j < 2; ++j) acc[i][j] = (f32x4_t)0.f;
    int fr = lane & 15, fo = (lane >> 4) * 8;
    for (int k0 = 0; k0 < K; k0 += 64) {
        #pragma unroll
        for (int i = 0; i < 2; ++i) {
            int ch = wid * 2 + i;
            const u16* ga = A + (size_t)(row0 + ch * 8 + l8) * K + k0 + l7 * 8;
            gload16(ga, &As[ch * 512]);
            const u16* gb = B + (size_t)(col0 + ch * 8 + l8) * K + k0 + l7 * 8;
            gload16(gb, &Bs[ch * 512]);
        }
        __syncthreads();
        __builtin_amdgcn_s_setprio(1);
        #pragma unroll
        for (int khf = 0; khf < 2; ++khf) {
            bf16x8_t bfrag[2];
            #pragma unroll
            for (int ni = 0; ni < 2; ++ni)
                bfrag[ni] = *(const bf16x8_t*)&Bs[(wc * 32 + ni * 16 + fr) * 64 + khf * 32 + fo];
            #pragma unroll
            for (int mi = 0; mi < 2; ++mi) {
                bf16x8_t af = *(const bf16x8_t*)&As[(wr * 32 + mi * 16 + fr) * 64 + khf * 32 + fo];
                #pragma unroll
                for (int ni = 0; ni < 2; ++ni)
                    acc[mi][ni] = __builtin_amdgcn_mfma_f32_16x16x32_bf16(
                        af, bfrag[ni], acc[mi][ni], 0, 0, 0);
            }
        }
        __builtin_amdgcn_s_setprio(0);
        __syncthreads();
    }
    int dr = (lane >> 4) * 4, dc = lane & 15;
    #pragma unroll
    for (int mi = 0; mi < 2; ++mi) {
        int gr = row0 + wr * 32 + mi * 16 + dr;
        #pragma unroll
        for (int ni = 0; ni < 2; ++ni) {
            int gc = col0 + wc * 32 + ni * 16 + dc;
            #pragma unroll
            for (int j = 0; j < 4; ++j) {
                size_t off = (size_t)(gr + j) * N + gc;
                Cf[off] = acc[mi][ni][j] + res[off];
            }
        }
    }
}

// ============ FUSED omega-rule + flash attention ============================
// 1-D grid, XCD head-locality AND complementary qt pairing:
//   hi = bit8, h = (b&7)*2 + hi, qt = hi ? 31-s5 : s5.
// 1-tile double-buffered loops, no-max softmax, b64 P-stores via cvt_pk and
// the s-column permutation pi(s)=(s&15)*4+(s>>4) pre-applied to khT/vhT.
// Omega's per-column factor colf = lambda^(q0-i)*gamma[i] is precomputed
// once per block into LDS (it is q0-constant), removing exp2+global loads
// from the per-tile critical path.
__global__ __launch_bounds__(256) void fused_omega_attn_kernel(
    const float* __restrict__ qhp, const u16* __restrict__ khp,
    const u16* __restrict__ khT, const u16* __restrict__ vhT,
    const float* __restrict__ gammab, const float* __restrict__ mp,
    const float* __restrict__ mg, u16* __restrict__ ao)
{
    __shared__ u16 Ks[2][KBLK][ALDK];
    __shared__ u16 Xt[2][KBLK][ALDK];
    __shared__ u16 Ps[QBLK][ALDK];
    __shared__ float colfL[CTX_W + KBLK];
    const int tid = threadIdx.x, lane = tid & 63, wq = tid >> 6;
    const int b = blockIdx.x;
    const int hi = (b >> 8) & 1;
    const int h = ((b & 7) << 1) + hi;
    const int s5 = (b >> 3) & 31;
    const int qt = hi ? (31 - s5) : s5;
    const int q0 = qt * QBLK;
    const int fr = lane & 15, g4 = lane >> 4;
    const int fko = g4 * 8;
    const int c = fr, rg = g4;
    const int si = tid >> 2, sdb = (tid & 3) * 16;
    const size_t hS = (size_t)h * S_LEN;
    const size_t hD = (size_t)h * HD_DIM;

    int rowt[4]; float rowf[4];
    #pragma unroll
    for (int j = 0; j < 4; ++j) {
        rowt[j] = q0 + wq * 16 + rg * 4 + j;
        rowf[j] = exp2f((float)(wq * 16 + rg * 4 + j) * L2LAM);
    }
    // q_old A-fragments (bf16)
    bf16x8_t qf[2];
    {
        const float* qrow = qhp + (hS + q0 + wq * 16 + fr) * HD_DIM;
        #pragma unroll
        for (int u = 0; u < 2; ++u) {
            float4 a = *(const float4*)(qrow + u * 32 + fko);
            float4 bq = *(const float4*)(qrow + u * 32 + fko + 4);
            bf16x8_t f;
            f[0]=f2bf(a.x); f[1]=f2bf(a.y); f[2]=f2bf(a.z); f[3]=f2bf(a.w);
            f[4]=f2bf(bq.x); f[5]=f2bf(bq.y); f[6]=f2bf(bq.z); f[7]=f2bf(bq.w);
            qf[u] = f;
        }
    }
    // ---------------- omega phase (double-buffered) ----------------
    f32x4_t accc[4];
    #pragma unroll
    for (int n = 0; n < 4; ++n) accc[n] = (f32x4_t)0.f;
    float wsum[4] = {0.f, 0.f, 0.f, 0.f};
    const int kt0 = (q0 > (CTX_W - 1)) ? (q0 - (CTX_W - 1)) / KBLK : 0;
    const int i0 = kt0 * KBLK;
    const int nwin = (qt + 1) * KBLK - i0;
    // precompute colf window (q0-constant) into LDS
    for (int idx = tid; idx < nwin; idx += 256) {
        int icol = i0 + idx;
        colfL[idx] = exp2f((float)(q0 - icol) * L2LAM) * gammab[icol];
    }
    {
        const u16* gk = khp + (hS + kt0 * KBLK + si) * HD_DIM + sdb;
        const u16* gx = khT + (hD + si) * S_LEN + kt0 * KBLK + sdb;
        *(bf16x8_t*)&Ks[0][si][sdb]     = *(const bf16x8_t*)gk;
        *(bf16x8_t*)&Ks[0][si][sdb + 8] = *(const bf16x8_t*)(gk + 8);
        *(bf16x8_t*)&Xt[0][si][sdb]     = *(const bf16x8_t*)gx;
        *(bf16x8_t*)&Xt[0][si][sdb + 8] = *(const bf16x8_t*)(gx + 8);
    }
    __syncthreads();
    int cur = 0;
    for (int kt = kt0; kt <= qt; ++kt) {
        const int k0 = kt * KBLK;
        const bool hn = (kt < qt);
        bf16x8_t nk0, nk1, nx0, nx1;
        if (hn) {
            const u16* gk = khp + (hS + k0 + KBLK + si) * HD_DIM + sdb;
            const u16* gx = khT + (hD + si) * S_LEN + k0 + KBLK + sdb;
            nk0 = *(const bf16x8_t*)gk; nk1 = *(const bf16x8_t*)(gk + 8);
            nx0 = *(const bf16x8_t*)gx; nx1 = *(const bf16x8_t*)(gx + 8);
        }
        f32x4_t s[4];
        #pragma unroll
        for (int n = 0; n < 4; ++n) s[n] = (f32x4_t)0.f;
        __builtin_amdgcn_s_setprio(1);
        #pragma unroll
        for (int u = 0; u < 2; ++u)
            #pragma unroll
            for (int n = 0; n < 4; ++n) {
                bf16x8_t kb = *(const bf16x8_t*)&Ks[cur][n * 16 + fr][u * 32 + fko];
                s[n] = __builtin_amdgcn_mfma_f32_16x16x32_bf16(qf[u], kb, s[n], 0, 0, 0);
            }
        __builtin_amdgcn_s_setprio(0);
        const bool boundary = (kt == kt0) || (kt == qt);
        float colf[4];
        #pragma unroll
        for (int n = 0; n < 4; ++n)
            colf[n] = colfL[k0 - i0 + n * 16 + c];
        #pragma unroll
        for (int j = 0; j < 4; ++j) {
            float pv[4];
            #pragma unroll
            for (int n = 0; n < 4; ++n) {
                float w;
                if (boundary) {
                    int delta = rowt[j] - (k0 + n * 16 + c);
                    w = (delta >= 0 && delta < CTX_W) ? rowf[j] * colf[n] : 0.f;
                } else {
                    w = rowf[j] * colf[n];
                }
                wsum[j] += w;
                pv[n] = w * s[n][j];
            }
            uint2 pk;
            pk.x = f2bf2(pv[0], pv[1]);
            pk.y = f2bf2(pv[2], pv[3]);
            *(uint2*)&Ps[wq * 16 + rg * 4 + j][c * 4] = pk;   // ds_write_b64
        }
        __builtin_amdgcn_s_setprio(1);
        #pragma unroll
        for (int u = 0; u < 2; ++u) {
            bf16x8_t pa = *(const bf16x8_t*)&Ps[wq * 16 + fr][u * 32 + fko];
            #pragma unroll
            for (int n = 0; n < 4; ++n) {
                bf16x8_t kb = *(const bf16x8_t*)&Xt[cur][n * 16 + fr][u * 32 + fko];
                accc[n] = __builtin_amdgcn_mfma_f32_16x16x32_bf16(pa, kb, accc[n], 0, 0, 0);
            }
        }
        __builtin_amdgcn_s_setprio(0);
        if (hn) {
            int nxt = cur ^ 1;
            *(bf16x8_t*)&Ks[nxt][si][sdb]     = nk0;
            *(bf16x8_t*)&Ks[nxt][si][sdb + 8] = nk1;
            *(bf16x8_t*)&Xt[nxt][si][sdb]     = nx0;
            *(bf16x8_t*)&Xt[nxt][si][sdb + 8] = nx1;
        }
        __syncthreads();
        cur ^= 1;
    }
    // persist = Q @ M_p^T
    f32x4_t pacc[4];
    #pragma unroll
    for (int n = 0; n < 4; ++n) pacc[n] = (f32x4_t)0.f;
    const float* mph = mp + hD * HD_DIM;
    #pragma unroll
    for (int u = 0; u < 2; ++u)
        #pragma unroll
        for (int n = 0; n < 4; ++n) {
            const float* br = mph + (size_t)(n * 16 + fr) * HD_DIM + u * 32 + fko;
            float4 a = *(const float4*)br;
            float4 bq = *(const float4*)(br + 4);
            bf16x8_t f;
            f[0]=f2bf(a.x); f[1]=f2bf(a.y); f[2]=f2bf(a.z); f[3]=f2bf(a.w);
            f[4]=f2bf(bq.x); f[5]=f2bf(bq.y); f[6]=f2bf(bq.z); f[7]=f2bf(bq.w);
            pacc[n] = __builtin_amdgcn_mfma_f32_16x16x32_bf16(qf[u], f, pacc[n], 0, 0, 0);
        }
    #pragma unroll
    for (int j = 0; j < 4; ++j) {
        wsum[j] += __shfl_xor(wsum[j], 1);
        wsum[j] += __shfl_xor(wsum[j], 2);
        wsum[j] += __shfl_xor(wsum[j], 4);
        wsum[j] += __shfl_xor(wsum[j], 8);
    }
    float gate = 1.f / (1.f + __expf(-mg[0]));
    float keep = 1.f - gate;
    // q_new (pre-scaled by 0.125*log2e) -> wave-private rows (d-domain, scalar)
    #pragma unroll
    for (int n = 0; n < 4; ++n) {
        #pragma unroll
        for (int j = 0; j < 4; ++j) {
            float qold = qhp[(hS + rowt[j]) * HD_DIM + n * 16 + c];
            float qn = keep * qold + gate * (pacc[n][j] + accc[n][j]) / (1.f + wsum[j]);
            Ps[wq * 16 + rg * 4 + j][n * 16 + c] = f2bf(qn * QSCALE);
        }
    }
    bf16x8_t qf2[2];
    #pragma unroll
    for (int u = 0; u < 2; ++u)
        qf2[u] = *(const bf16x8_t*)&Ps[wq * 16 + fr][u * 32 + fko];

    // ---------------- attention phase (double-buffered, no-max softmax) -----
    f32x4_t acco[4];
    #pragma unroll
    for (int n = 0; n < 4; ++n) acco[n] = (f32x4_t)0.f;
    float l_run[4] = {0.f, 0.f, 0.f, 0.f};
    {   // prologue: stage tile 0 into buffer 0 (all omega reads done)
        const u16* gk = khp + (hS + si) * HD_DIM + sdb;
        const u16* gv = vhT + (hD + si) * S_LEN + sdb;
        *(bf16x8_t*)&Ks[0][si][sdb]     = *(const bf16x8_t*)gk;
        *(bf16x8_t*)&Ks[0][si][sdb + 8] = *(const bf16x8_t*)(gk + 8);
        *(bf16x8_t*)&Xt[0][si][sdb]     = *(const bf16x8_t*)gv;
        *(bf16x8_t*)&Xt[0][si][sdb + 8] = *(const bf16x8_t*)(gv + 8);
    }
    __syncthreads();
    cur = 0;
    for (int kt = 0; kt <= qt; ++kt) {
        const int k0 = kt * KBLK;
        const bool hn = (kt < qt);
        bf16x8_t nk0, nk1, nv0, nv1;
        if (hn) {
            const u16* gk = khp + (hS + k0 + KBLK + si) * HD_DIM + sdb;
            const u16* gv = vhT + (hD + si) * S_LEN + k0 + KBLK + sdb;
            nk0 = *(const bf16x8_t*)gk; nk1 = *(const bf16x8_t*)(gk + 8);
            nv0 = *(const bf16x8_t*)gv; nv1 = *(const bf16x8_t*)(gv + 8);
        }
        f32x4_t s[4];
        #pragma unroll
        for (int n = 0; n < 4; ++n) s[n] = (f32x4_t)0.f;
        __builtin_amdgcn_s_setprio(1);
        #pragma unroll
        for (int u = 0; u < 2; ++u)
            #pragma unroll
            for (int n = 0; n < 4; ++n) {
                bf16x8_t kb = *(const bf16x8_t*)&Ks[cur][n * 16 + fr][u * 32 + fko];
                s[n] = __builtin_amdgcn_mfma_f32_16x16x32_bf16(qf2[u], kb, s[n], 0, 0, 0);
            }
        __builtin_amdgcn_s_setprio(0);
        if (kt == qt) {   // causal mask only on diagonal tile
            #pragma unroll
            for (int n = 0; n < 4; ++n) {
                int icol = k0 + n * 16 + c;
                #pragma unroll
                for (int j = 0; j < 4; ++j)
                    if (icol > rowt[j]) s[n][j] = -1e30f;
            }
        }
        #pragma unroll
        for (int j = 0; j < 4; ++j) {
            float p0 = exp2f(s[0][j]);
            float p1 = exp2f(s[1][j]);
            float p2 = exp2f(s[2][j]);
            float p3 = exp2f(s[3][j]);
            l_run[j] += (p0 + p1) + (p2 + p3);
            uint2 pk;
            pk.x = f2bf2(p0, p1);
            pk.y = f2bf2(p2, p3);
            *(uint2*)&Ps[wq * 16 + rg * 4 + j][c * 4] = pk;   // ds_write_b64
        }
        __builtin_amdgcn_s_setprio(1);
        #pragma unroll
        for (int u = 0; u < 2; ++u) {
            bf16x8_t pa = *(const bf16x8_t*)&Ps[wq * 16 + fr][u * 32 + fko];
            #pragma unroll
            for (int n = 0; n < 4; ++n) {
                bf16x8_t vb = *(const bf16x8_t*)&Xt[cur][n * 16 + fr][u * 32 + fko];
                acco[n] = __builtin_amdgcn_mfma_f32_16x16x32_bf16(pa, vb, acco[n], 0, 0, 0);
            }
        }
        __builtin_amdgcn_s_setprio(0);
        if (hn) {
            int nxt = cur ^ 1;
            *(bf16x8_t*)&Ks[nxt][si][sdb]     = nk0;
            *(bf16x8_t*)&Ks[nxt][si][sdb + 8] = nk1;
            *(bf16x8_t*)&Xt[nxt][si][sdb]     = nv0;
            *(bf16x8_t*)&Xt[nxt][si][sdb + 8] = nv1;
        }
        __syncthreads();
        cur ^= 1;
    }
    #pragma unroll
    for (int j = 0; j < 4; ++j) {
        l_run[j] += __shfl_xor(l_run[j], 1);
        l_run[j] += __shfl_xor(l_run[j], 2);
        l_run[j] += __shfl_xor(l_run[j], 4);
        l_run[j] += __shfl_xor(l_run[j], 8);
    }
    #pragma unroll
    for (int n = 0; n < 4; ++n) {
        #pragma unroll
        for (int j = 0; j < 4; ++j) {
            float o = acco[n][j] / l_run[j];
            ao[(size_t)rowt[j] * D_DIM + h * HD_DIM + n * 16 + c] = f2bf(o);
        }
    }
}

extern "C" void kernel_launch(void* const* d_in, const int* in_sizes, int n_in,
                              void* d_out, int out_size, void* d_ws, size_t ws_size,
                              hipStream_t stream) {
    const float* x         = (const float*)d_in[0];
    const float* norm1_w   = (const float*)d_in[1];
    const float* norm2_w   = (const float*)d_in[2];
    const float* w_qkv     = (const float*)d_in[3];
    const float* q_norm_w  = (const float*)d_in[4];
    const float* k_norm_w  = (const float*)d_in[5];
    const float* gamma_w1  = (const float*)d_in[6];
    const float* gamma_w2  = (const float*)d_in[7];
    const float* m_persist = (const float*)d_in[8];
    const float* mem_gate  = (const float*)d_in[9];
    const float* w_o       = (const float*)d_in[10];
    const float* ffn_w1    = (const float*)d_in[11];
    const float* ffn_w3    = (const float*)d_in[12];
    const float* ffn_w2    = (const float*)d_in[13];
    float* out = (float*)d_out;
    char* ws = (char*)d_ws;

    const size_t MB = 1024 * 1024;
    u16*   h_bf   = (u16*)(ws);                 // [0,4MB) h / h2
    u16*   wqT    = (u16*)(ws + 4 * MB);        // [4,10)
    u16*   woT    = (u16*)(ws + 10 * MB);       // [10,12)
    u16*   w13T   = (u16*)(ws + 12 * MB);       // [12,23) interleaved w1/w3
    u16*   w2T    = (u16*)(ws + 23 * MB);       // [23,28.5)
    u16*   qkv_bf = (u16*)(ws + 29884416);      // [28.5,40.5) dead after split
    u16*   ao_bf  = (u16*)(ws + 38273024);      // [36.5,40.5) (after qkv dead)
    float* qh     = (float*)(ws + 42467328);    // [40.5,48.5) fp32 q
    u16*   kh     = (u16*)(ws + 50855936);      // [48.5,52.5)
    u16*   khT_s  = (u16*)(ws + 50855936 + 4 * MB);   // [52.5,56.5)
    float* gammab = (float*)(ws + 59244544);    // [56.5,+8KB)
    u16*   vhT_s  = (u16*)(ws + 59244544 + 64 * 1024); // [56.5+64KB,+4MB)
    u16*   mid_bf = (u16*)(ws + 29884416);      // [28.5,40) post-attention

    // --- all weight transposes in ONE launch ---------------------------------
    hipLaunchKernelGGL(transpose_all_kernel, dim3(12544), dim3(256), 0, stream,
                       w_qkv, w_o, ffn_w1, ffn_w3, ffn_w2, wqT, woT, w13T, w2T);

    // --- forward pass ---------------------------------------------------------
    // rmsnorm1 + gamma gate fused
    hipLaunchKernelGGL((rmsnorm_gamma_kernel<true>), dim3(S_LEN), dim3(256), 0, stream,
                       x, norm1_w, h_bf, gamma_w1, gamma_w2, gammab);
    hipLaunchKernelGGL((gemm_bb_kernel<64, 1>), dim3(24, 32), dim3(256), 0, stream,
                       h_bf, wqT, qkv_bf, S_LEN, 3 * D_DIM, D_DIM);
    hipLaunchKernelGGL(split_rope_tr_kernel, dim3(S_LEN / 64, H_NUM), dim3(256), 0, stream,
                       qkv_bf, q_norm_w, k_norm_w, qh, kh, khT_s, vhT_s);
    hipLaunchKernelGGL(fused_omega_attn_kernel, dim3(512), dim3(256), 0, stream,
                       qh, kh, khT_s, vhT_s, gammab, m_persist, mem_gate, ao_bf);
    hipLaunchKernelGGL(gemm64_kernel, dim3(16, 32), dim3(256), 0, stream,
                       ao_bf, woT, x, out, S_LEN, D_DIM, D_DIM);
    hipLaunchKernelGGL((rmsnorm_gamma_kernel<false>), dim3(S_LEN), dim3(256), 0, stream,
                       out, norm2_w, h_bf, (const float*)nullptr,
                       (const float*)nullptr, (float*)nullptr);
    // ffn13 GEMM with fused SwiGLU epilogue -> mid (N=5632 compute, 2816 out)
    hipLaunchKernelGGL((gemm_bb_kernel<64, 2>), dim3(44, 32), dim3(256), 0, stream,
                       h_bf, w13T, mid_bf, S_LEN, 2 * FFNP, D_DIM);
    hipLaunchKernelGGL(gemm64_kernel, dim3(16, 32), dim3(256), 0, stream,
                       mid_bf, w2T, out, out, S_LEN, D_DIM, FFNP);
}

// Round 16
// 225.841 us; speedup vs baseline: 1.0882x; 1.0412x over previous
//
#include <hip/hip_runtime.h>
#include <hip/hip_bf16.h>

#define S_LEN 2048
#define D_DIM 1024
#define H_NUM 16
#define HD_DIM 64
#define GH_DIM 64
#define FFN_H 2730
#define FFNP  2816          // FFN_H padded to multiple of 128 (zero-filled)
#define CTX_W 512
#define L2LAM -0.00144341687f   // log2(0.999)
#define QBLK 64
#define KBLK 64
#define ALDK 76             // LDS row stride (152B): write-conflict-free, reads <=2-way
#define QSCALE 0.1803368801111731f  // 0.125 * log2(e): scores come out ready for exp2

typedef unsigned short u16;
typedef __attribute__((ext_vector_type(8))) short bf16x8_t;
typedef __attribute__((ext_vector_type(4))) float f32x4_t;

__device__ inline float wave_sum(float v) {
    for (int off = 32; off; off >>= 1) v += __shfl_xor(v, off);
    return v;
}
// f32 -> bf16 (RNE) via the HW pack instruction: 1 VALU op.
__device__ inline u16 f2bf(float f) {
    unsigned r;
    asm("v_cvt_pk_bf16_f32 %0, %1, %2" : "=v"(r) : "v"(f), "v"(f));
    return (u16)r;
}
// pack two f32 -> u32 of 2 bf16 (lo, hi): 1 VALU op.
__device__ inline unsigned f2bf2(float lo, float hi) {
    unsigned r;
    asm("v_cvt_pk_bf16_f32 %0, %1, %2" : "=v"(r) : "v"(lo), "v"(hi));
    return r;
}
__device__ inline float bf2f(u16 u) {
    return __uint_as_float(((unsigned int)u) << 16);
}
__device__ inline void gload16(const void* g, void* l) {
    __builtin_amdgcn_global_load_lds(
        (const __attribute__((address_space(1))) void*)g,
        (__attribute__((address_space(3))) void*)l, 16, 0, 0);
}

// ------- RMSNorm (fp32 in -> bf16 out), optionally fused gamma gate ---------
template<bool GAMMA>
__global__ __launch_bounds__(256) void rmsnorm_gamma_kernel(
    const float* __restrict__ in, const float* __restrict__ w,
    u16* __restrict__ out, const float* __restrict__ w1,
    const float* __restrict__ w2, float* __restrict__ gamma)
{
    __shared__ float hl[D_DIM];
    __shared__ float part[4][GH_DIM];
    __shared__ float wsum[4];
    int row = blockIdx.x;
    int tid = threadIdx.x, lane = tid & 63, wv = tid >> 6;
    const float4* ir = reinterpret_cast<const float4*>(in + (size_t)row * D_DIM);
    float4 v = ir[tid];
    float ss = v.x*v.x + v.y*v.y + v.z*v.z + v.w*v.w;
    ss = wave_sum(ss);
    if (lane == 0) wsum[wv] = ss;
    __syncthreads();
    float tot = wsum[0] + wsum[1] + wsum[2] + wsum[3];
    float scale = rsqrtf(tot / (float)D_DIM + 1e-6f);
    const float4* wr = reinterpret_cast<const float4*>(w);
    float4 wv4 = wr[tid];
    float h0 = v.x * scale * wv4.x, h1 = v.y * scale * wv4.y;
    float h2 = v.z * scale * wv4.z, h3 = v.w * scale * wv4.w;
    uint2 o;
    o.x = f2bf2(h0, h1);
    o.y = f2bf2(h2, h3);
    *reinterpret_cast<uint2*>(out + (size_t)row * D_DIM + tid * 4) = o;
    if (GAMMA) {
        hl[tid*4+0] = h0; hl[tid*4+1] = h1; hl[tid*4+2] = h2; hl[tid*4+3] = h3;
        __syncthreads();
        float acc = 0.f;
        #pragma unroll 8
        for (int k = wv * 256; k < wv * 256 + 256; ++k)
            acc += hl[k] * w1[k * GH_DIM + lane];
        part[wv][lane] = acc;
        __syncthreads();
        if (wv == 0) {
            float t = part[0][lane] + part[1][lane] + part[2][lane] + part[3][lane];
            float z = t / (1.f + __expf(-t));
            float y = z * w2[lane];
            float t2 = wave_sum(y);
            if (lane == 0) gamma[row] = 1.f / (1.f + __expf(-t2));
        }
    }
}

// --- prep: weight transposes + rmsnorm1 + gamma gate, ONE launch ------------
// Blocks [0,12544) do the 5 weight transpose segments; blocks [12544,14592)
// do rmsnorm1+gamma for row = b-12544. The two halves are data-independent
// and overlap on the machine instead of serializing as two dispatches.
__global__ __launch_bounds__(256) void prep_kernel(
    const float* __restrict__ w_qkv, const float* __restrict__ w_o,
    const float* __restrict__ w1f, const float* __restrict__ w3f,
    const float* __restrict__ w2f, u16* __restrict__ wqT,
    u16* __restrict__ woT, u16* __restrict__ w13T, u16* __restrict__ w2T,
    const float* __restrict__ x, const float* __restrict__ norm1_w,
    u16* __restrict__ h_bf, const float* __restrict__ gw1,
    const float* __restrict__ gw2, float* __restrict__ gamma)
{
    __shared__ float tile[32][33];
    __shared__ float hl[D_DIM];
    __shared__ float part[4][GH_DIM];
    __shared__ float wsum[4];
    int b = blockIdx.x;
    int tid = threadIdx.x;
    if (b < 12544) {
        const float* src; u16* dst;
        int srcK, srcN, Kp, rowOff, rowMul, nbx;
        if (b < 3072)      {           src = w_qkv; dst = wqT;  srcK = 1024; srcN = 3072; Kp = 1024; rowOff = 0; rowMul = 1; nbx = 96; }
        else if (b < 4096) { b -= 3072; src = w_o;  dst = woT;  srcK = 1024; srcN = 1024; Kp = 1024; rowOff = 0; rowMul = 1; nbx = 32; }
        else if (b < 6912) { b -= 4096; src = w1f;  dst = w13T; srcK = 1024; srcN = 2730; Kp = 1024; rowOff = 0; rowMul = 2; nbx = 88; }
        else if (b < 9728) { b -= 6912; src = w3f;  dst = w13T; srcK = 1024; srcN = 2730; Kp = 1024; rowOff = 1; rowMul = 2; nbx = 88; }
        else               { b -= 9728; src = w2f;  dst = w2T;  srcK = 2730; srcN = 1024; Kp = 2816; rowOff = 0; rowMul = 1; nbx = 32; }
        int n0 = (b % nbx) * 32, k0 = (b / nbx) * 32;
        int tx = tid & 31, ty = tid >> 5;
        #pragma unroll
        for (int p = 0; p < 4; ++p) {
            int kk = ty + p * 8;
            int r = k0 + kk, c = n0 + tx;
            tile[kk][tx] = (r < srcK && c < srcN) ? src[(size_t)r * srcN + c] : 0.f;
        }
        __syncthreads();
        #pragma unroll
        for (int p = 0; p < 4; ++p) {
            int nn = ty + p * 8;
            dst[(size_t)(rowOff + (n0 + nn) * rowMul) * Kp + k0 + tx] = f2bf(tile[tx][nn]);
        }
    } else {
        int row = b - 12544;
        int lane = tid & 63, wv = tid >> 6;
        const float4* ir = reinterpret_cast<const float4*>(x + (size_t)row * D_DIM);
        float4 v = ir[tid];
        float ss = v.x*v.x + v.y*v.y + v.z*v.z + v.w*v.w;
        ss = wave_sum(ss);
        if (lane == 0) wsum[wv] = ss;
        __syncthreads();
        float tot = wsum[0] + wsum[1] + wsum[2] + wsum[3];
        float scale = rsqrtf(tot / (float)D_DIM + 1e-6f);
        const float4* wr = reinterpret_cast<const float4*>(norm1_w);
        float4 wv4 = wr[tid];
        float h0 = v.x * scale * wv4.x, h1 = v.y * scale * wv4.y;
        float h2 = v.z * scale * wv4.z, h3 = v.w * scale * wv4.w;
        uint2 o;
        o.x = f2bf2(h0, h1);
        o.y = f2bf2(h2, h3);
        *reinterpret_cast<uint2*>(h_bf + (size_t)row * D_DIM + tid * 4) = o;
        hl[tid*4+0] = h0; hl[tid*4+1] = h1; hl[tid*4+2] = h2; hl[tid*4+3] = h3;
        __syncthreads();
        float acc = 0.f;
        #pragma unroll 8
        for (int k = wv * 256; k < wv * 256 + 256; ++k)
            acc += hl[k] * gw1[k * GH_DIM + lane];
        part[wv][lane] = acc;
        __syncthreads();
        if (wv == 0) {
            float t = part[0][lane] + part[1][lane] + part[2][lane] + part[3][lane];
            float z = t / (1.f + __expf(-t));
            float y = z * gw2[lane];
            float t2 = wave_sum(y);
            if (lane == 0) gamma[row] = 1.f / (1.f + __expf(-t2));
        }
    }
}

// ---- fused split qkv + qk rmsnorm + RoPE + KV transpose (one launch) -------
__global__ __launch_bounds__(256) void split_rope_tr_kernel(
    const u16* __restrict__ qkv, const float* __restrict__ qw,
    const float* __restrict__ kw, float* __restrict__ qhp,
    u16* __restrict__ khp, u16* __restrict__ khT, u16* __restrict__ vhT)
{
    __shared__ u16 tk[64][ALDK];
    __shared__ u16 tv[64][ALDK];
    int tid = threadIdx.x;
    int w = tid >> 6, d = tid & 63;
    int h = blockIdx.y;
    int s0 = blockIdx.x * 64;
    float qwv = qw[d], kwv = kw[d];
    int j = d & 31;
    float inv = expf(-(float)j * (9.2103403719761836f / 32.0f));
    float sgn = (d < 32) ? -1.f : 1.f;
    for (int i = 0; i < 16; ++i) {
        int sl = w * 16 + i;
        int s = s0 + sl;
        size_t base = (size_t)s * (3 * D_DIM) + h * HD_DIM + d;
        float qv = bf2f(qkv[base]);
        float kv = bf2f(qkv[base + D_DIM]);
        u16  vv = qkv[base + 2 * D_DIM];
        float sq = wave_sum(qv * qv);
        float qn = qv * rsqrtf(sq / (float)HD_DIM + 1e-6f) * qwv;
        float sk = wave_sum(kv * kv);
        float kn = kv * rsqrtf(sk / (float)HD_DIM + 1e-6f) * kwv;
        float ang = (float)s * inv;
        float cs = cosf(ang), sn = sinf(ang);
        float qp = __shfl_xor(qn, 32);
        float kp = __shfl_xor(kn, 32);
        float qo = qn * cs + sgn * qp * sn;
        float ko = kn * cs + sgn * kp * sn;
        size_t ob = ((size_t)h * S_LEN + s) * HD_DIM + d;
        u16 kb = f2bf(ko);
        qhp[ob] = qo;
        khp[ob] = kb;
        tk[sl][d] = kb;
        tv[sl][d] = vv;
    }
    __syncthreads();
    int r = tid >> 2, cc = (tid & 3) * 16;
    union { u16 u[16]; bf16x8_t v[2]; } ok, ov;
    #pragma unroll
    for (int e = 0; e < 16; ++e) {
        int ksrc = (e & 3) * 16 + (tid & 3) * 4 + (e >> 2);   // pi^-1 permute
        ok.u[e] = tk[ksrc][r]; ov.u[e] = tv[ksrc][r];
    }
    u16* kd = khT + ((size_t)h * HD_DIM + r) * S_LEN + s0 + cc;
    u16* vd = vhT + ((size_t)h * HD_DIM + r) * S_LEN + s0 + cc;
    *(bf16x8_t*)kd       = ok.v[0];
    *(bf16x8_t*)(kd + 8) = ok.v[1];
    *(bf16x8_t*)vd       = ov.v[0];
    *(bf16x8_t*)(vd + 8) = ov.v[1];
}

// ---------------- bf16 MFMA GEMM, 128-col tiles ------------------------------
// MODE 1: bf16 out.  MODE 2: paired silu-mul, bf16 out width N/2.
template<int BM, int MODE>
__global__ __launch_bounds__(256) void gemm_bb_kernel(
    const u16* __restrict__ A, const u16* __restrict__ B,
    u16* __restrict__ Cb, int M, int N, int K)
{
    constexpr int MREP = BM / 32;
    constexpr int ACH  = BM / 32;
    __shared__ u16 As[BM * 64];
    __shared__ u16 Bs[128 * 64];
    int tid = threadIdx.x, lane = tid & 63, wid = tid >> 6;
    int wr = wid >> 1, wc = wid & 1;
    int row0 = blockIdx.y * BM, col0 = blockIdx.x * 128;
    int l8 = lane >> 3, l7 = lane & 7;
    f32x4_t acc[MREP][4];
    #pragma unroll
    for (int i = 0; i < MREP; ++i)
        #pragma unroll
        for (int j = 0; j < 4; ++j) acc[i][j] = (f32x4_t)0.f;

    int fr = lane & 15, fo = (lane >> 4) * 8;
    for (int k0 = 0; k0 < K; k0 += 64) {
        #pragma unroll
        for (int i = 0; i < ACH; ++i) {
            int ch = wid * ACH + i;
            const u16* ga = A + (size_t)(row0 + ch * 8 + l8) * K + k0 + l7 * 8;
            gload16(ga, &As[ch * 512]);
        }
        #pragma unroll
        for (int i = 0; i < 4; ++i) {
            int ch = wid * 4 + i;
            const u16* gb = B + (size_t)(col0 + ch * 8 + l8) * K + k0 + l7 * 8;
            gload16(gb, &Bs[ch * 512]);
        }
        __syncthreads();
        __builtin_amdgcn_s_setprio(1);
        #pragma unroll
        for (int khf = 0; khf < 2; ++khf) {
            bf16x8_t bfrag[4];
            #pragma unroll
            for (int ni = 0; ni < 4; ++ni)
                bfrag[ni] = *(const bf16x8_t*)&Bs[(wc * 64 + ni * 16 + fr) * 64 + khf * 32 + fo];
            #pragma unroll
            for (int mi = 0; mi < MREP; ++mi) {
                bf16x8_t af = *(const bf16x8_t*)&As[(wr * (BM / 2) + mi * 16 + fr) * 64 + khf * 32 + fo];
                #pragma unroll
                for (int ni = 0; ni < 4; ++ni)
                    acc[mi][ni] = __builtin_amdgcn_mfma_f32_16x16x32_bf16(
                        af, bfrag[ni], acc[mi][ni], 0, 0, 0);
            }
        }
        __builtin_amdgcn_s_setprio(0);
        __syncthreads();
    }
    int dr = (lane >> 4) * 4, dc = lane & 15;
    #pragma unroll
    for (int mi = 0; mi < MREP; ++mi) {
        int gr = row0 + wr * (BM / 2) + mi * 16 + dr;
        #pragma unroll
        for (int ni = 0; ni < 4; ++ni) {
            int gc = col0 + wc * 64 + ni * 16 + dc;
            #pragma unroll
            for (int j = 0; j < 4; ++j) {
                float v = acc[mi][ni][j];
                if (MODE == 1) {
                    Cb[(size_t)(gr + j) * N + gc] = f2bf(v);
                } else {
                    float partner = __shfl_xor(v, 1);
                    float a1 = (dc & 1) ? partner : v;
                    float a3 = (dc & 1) ? v : partner;
                    float rr = a1 / (1.f + __expf(-a1)) * a3;
                    if (!(dc & 1))
                        Cb[(size_t)(gr + j) * (N >> 1) + (gc >> 1)] = f2bf(rr);
                }
            }
        }
    }
}

// ---------------- bf16 MFMA GEMM, 64x64 tiles, fp32 out + residual ----------
__global__ __launch_bounds__(256) void gemm64_kernel(
    const u16* __restrict__ A, const u16* __restrict__ B,
    const float* __restrict__ res, float* __restrict__ Cf,
    int M, int N, int K)
{
    __shared__ u16 As[64 * 64];
    __shared__ u16 Bs[64 * 64];
    int tid = threadIdx.x, lane = tid & 63, wid = tid >> 6;
    int wr = wid >> 1, wc = wid & 1;
    int row0 = blockIdx.y * 64, col0 = blockIdx.x * 64;
    int l8 = lane >> 3, l7 = lane & 7;
    f32x4_t acc[2][2];
    #pragma unroll
    for (int i = 0; i < 2; ++i)
        #pragma unroll
        for (int j = 0; j < 2; ++j) acc[i][j] = (f32x4_t)0.f;
    int fr = lane & 15, fo = (lane >> 4) * 8;
    for (int k0 = 0; k0 < K; k0 += 64) {
        #pragma unroll
        for (int i = 0; i < 2; ++i) {
            int ch = wid * 2 + i;
            const u16* ga = A + (size_t)(row0 + ch * 8 + l8) * K + k0 + l7 * 8;
            gload16(ga, &As[ch * 512]);
            const u16* gb = B + (size_t)(col0 + ch * 8 + l8) * K + k0 + l7 * 8;
            gload16(gb, &Bs[ch * 512]);
        }
        __syncthreads();
        __builtin_amdgcn_s_setprio(1);
        #pragma unroll
        for (int khf = 0; khf < 2; ++khf) {
            bf16x8_t bfrag[2];
            #pragma unroll
            for (int ni = 0; ni < 2; ++ni)
                bfrag[ni] = *(const bf16x8_t*)&Bs[(wc * 32 + ni * 16 + fr) * 64 + khf * 32 + fo];
            #pragma unroll
            for (int mi = 0; mi < 2; ++mi) {
                bf16x8_t af = *(const bf16x8_t*)&As[(wr * 32 + mi * 16 + fr) * 64 + khf * 32 + fo];
                #pragma unroll
                for (int ni = 0; ni < 2; ++ni)
                    acc[mi][ni] = __builtin_amdgcn_mfma_f32_16x16x32_bf16(
                        af, bfrag[ni], acc[mi][ni], 0, 0, 0);
            }
        }
        __builtin_amdgcn_s_setprio(0);
        __syncthreads();
    }
    int dr = (lane >> 4) * 4, dc = lane & 15;
    #pragma unroll
    for (int mi = 0; mi < 2; ++mi) {
        int gr = row0 + wr * 32 + mi * 16 + dr;
        #pragma unroll
        for (int ni = 0; ni < 2; ++ni) {
            int gc = col0 + wc * 32 + ni * 16 + dc;
            #pragma unroll
            for (int j = 0; j < 4; ++j) {
                size_t off = (size_t)(gr + j) * N + gc;
                Cf[off] = acc[mi][ni][j] + res[off];
            }
        }
    }
}

// ============ FUSED omega-rule + flash attention ============================
__global__ __launch_bounds__(256) void fused_omega_attn_kernel(
    const float* __restrict__ qhp, const u16* __restrict__ khp,
    const u16* __restrict__ khT, const u16* __restrict__ vhT,
    const float* __restrict__ gammab, const float* __restrict__ mp,
    const float* __restrict__ mg, u16* __restrict__ ao)
{
    __shared__ u16 Ks[2][KBLK][ALDK];
    __shared__ u16 Xt[2][KBLK][ALDK];
    __shared__ u16 Ps[QBLK][ALDK];
    __shared__ float colfL[CTX_W + KBLK];
    const int tid = threadIdx.x, lane = tid & 63, wq = tid >> 6;
    const int b = blockIdx.x;
    const int hi = (b >> 8) & 1;
    const int h = ((b & 7) << 1) + hi;
    const int s5 = (b >> 3) & 31;
    const int qt = hi ? (31 - s5) : s5;
    const int q0 = qt * QBLK;
    const int fr = lane & 15, g4 = lane >> 4;
    const int fko = g4 * 8;
    const int c = fr, rg = g4;
    const int si = tid >> 2, sdb = (tid & 3) * 16;
    const size_t hS = (size_t)h * S_LEN;
    const size_t hD = (size_t)h * HD_DIM;

    int rowt[4]; float rowf[4];
    #pragma unroll
    for (int j = 0; j < 4; ++j) {
        rowt[j] = q0 + wq * 16 + rg * 4 + j;
        rowf[j] = exp2f((float)(wq * 16 + rg * 4 + j) * L2LAM);
    }
    bf16x8_t qf[2];
    {
        const float* qrow = qhp + (hS + q0 + wq * 16 + fr) * HD_DIM;
        #pragma unroll
        for (int u = 0; u < 2; ++u) {
            float4 a = *(const float4*)(qrow + u * 32 + fko);
            float4 bq = *(const float4*)(qrow + u * 32 + fko + 4);
            bf16x8_t f;
            f[0]=f2bf(a.x); f[1]=f2bf(a.y); f[2]=f2bf(a.z); f[3]=f2bf(a.w);
            f[4]=f2bf(bq.x); f[5]=f2bf(bq.y); f[6]=f2bf(bq.z); f[7]=f2bf(bq.w);
            qf[u] = f;
        }
    }
    // ---------------- omega phase (double-buffered) ----------------
    f32x4_t accc[4];
    #pragma unroll
    for (int n = 0; n < 4; ++n) accc[n] = (f32x4_t)0.f;
    float wsum[4] = {0.f, 0.f, 0.f, 0.f};
    const int kt0 = (q0 > (CTX_W - 1)) ? (q0 - (CTX_W - 1)) / KBLK : 0;
    const int i0 = kt0 * KBLK;
    const int nwin = (qt + 1) * KBLK - i0;
    for (int idx = tid; idx < nwin; idx += 256) {
        int icol = i0 + idx;
        colfL[idx] = exp2f((float)(q0 - icol) * L2LAM) * gammab[icol];
    }
    {
        const u16* gk = khp + (hS + kt0 * KBLK + si) * HD_DIM + sdb;
        const u16* gx = khT + (hD + si) * S_LEN + kt0 * KBLK + sdb;
        *(bf16x8_t*)&Ks[0][si][sdb]     = *(const bf16x8_t*)gk;
        *(bf16x8_t*)&Ks[0][si][sdb + 8] = *(const bf16x8_t*)(gk + 8);
        *(bf16x8_t*)&Xt[0][si][sdb]     = *(const bf16x8_t*)gx;
        *(bf16x8_t*)&Xt[0][si][sdb + 8] = *(const bf16x8_t*)(gx + 8);
    }
    __syncthreads();
    int cur = 0;
    for (int kt = kt0; kt <= qt; ++kt) {
        const int k0 = kt * KBLK;
        const bool hn = (kt < qt);
        bf16x8_t nk0, nk1, nx0, nx1;
        if (hn) {
            const u16* gk = khp + (hS + k0 + KBLK + si) * HD_DIM + sdb;
            const u16* gx = khT + (hD + si) * S_LEN + k0 + KBLK + sdb;
            nk0 = *(const bf16x8_t*)gk; nk1 = *(const bf16x8_t*)(gk + 8);
            nx0 = *(const bf16x8_t*)gx; nx1 = *(const bf16x8_t*)(gx + 8);
        }
        f32x4_t s[4];
        #pragma unroll
        for (int n = 0; n < 4; ++n) s[n] = (f32x4_t)0.f;
        __builtin_amdgcn_s_setprio(1);
        #pragma unroll
        for (int u = 0; u < 2; ++u)
            #pragma unroll
            for (int n = 0; n < 4; ++n) {
                bf16x8_t kb = *(const bf16x8_t*)&Ks[cur][n * 16 + fr][u * 32 + fko];
                s[n] = __builtin_amdgcn_mfma_f32_16x16x32_bf16(qf[u], kb, s[n], 0, 0, 0);
            }
        __builtin_amdgcn_s_setprio(0);
        const bool boundary = (kt == kt0) || (kt == qt);
        float colf[4];
        #pragma unroll
        for (int n = 0; n < 4; ++n)
            colf[n] = colfL[k0 - i0 + n * 16 + c];
        #pragma unroll
        for (int j = 0; j < 4; ++j) {
            float pv[4];
            #pragma unroll
            for (int n = 0; n < 4; ++n) {
                float w;
                if (boundary) {
                    int delta = rowt[j] - (k0 + n * 16 + c);
                    w = (delta >= 0 && delta < CTX_W) ? rowf[j] * colf[n] : 0.f;
                } else {
                    w = rowf[j] * colf[n];
                }
                wsum[j] += w;
                pv[n] = w * s[n][j];
            }
            uint2 pk;
            pk.x = f2bf2(pv[0], pv[1]);
            pk.y = f2bf2(pv[2], pv[3]);
            *(uint2*)&Ps[wq * 16 + rg * 4 + j][c * 4] = pk;   // ds_write_b64
        }
        __builtin_amdgcn_s_setprio(1);
        #pragma unroll
        for (int u = 0; u < 2; ++u) {
            bf16x8_t pa = *(const bf16x8_t*)&Ps[wq * 16 + fr][u * 32 + fko];
            #pragma unroll
            for (int n = 0; n < 4; ++n) {
                bf16x8_t kb = *(const bf16x8_t*)&Xt[cur][n * 16 + fr][u * 32 + fko];
                accc[n] = __builtin_amdgcn_mfma_f32_16x16x32_bf16(pa, kb, accc[n], 0, 0, 0);
            }
        }
        __builtin_amdgcn_s_setprio(0);
        if (hn) {
            int nxt = cur ^ 1;
            *(bf16x8_t*)&Ks[nxt][si][sdb]     = nk0;
            *(bf16x8_t*)&Ks[nxt][si][sdb + 8] = nk1;
            *(bf16x8_t*)&Xt[nxt][si][sdb]     = nx0;
            *(bf16x8_t*)&Xt[nxt][si][sdb + 8] = nx1;
        }
        __syncthreads();
        cur ^= 1;
    }
    // persist = Q @ M_p^T
    f32x4_t pacc[4];
    #pragma unroll
    for (int n = 0; n < 4; ++n) pacc[n] = (f32x4_t)0.f;
    const float* mph = mp + hD * HD_DIM;
    #pragma unroll
    for (int u = 0; u < 2; ++u)
        #pragma unroll
        for (int n = 0; n < 4; ++n) {
            const float* br = mph + (size_t)(n * 16 + fr) * HD_DIM + u * 32 + fko;
            float4 a = *(const float4*)br;
            float4 bq = *(const float4*)(br + 4);
            bf16x8_t f;
            f[0]=f2bf(a.x); f[1]=f2bf(a.y); f[2]=f2bf(a.z); f[3]=f2bf(a.w);
            f[4]=f2bf(bq.x); f[5]=f2bf(bq.y); f[6]=f2bf(bq.z); f[7]=f2bf(bq.w);
            pacc[n] = __builtin_amdgcn_mfma_f32_16x16x32_bf16(qf[u], f, pacc[n], 0, 0, 0);
        }
    #pragma unroll
    for (int j = 0; j < 4; ++j) {
        wsum[j] += __shfl_xor(wsum[j], 1);
        wsum[j] += __shfl_xor(wsum[j], 2);
        wsum[j] += __shfl_xor(wsum[j], 4);
        wsum[j] += __shfl_xor(wsum[j], 8);
    }
    float gate = 1.f / (1.f + __expf(-mg[0]));
    float keep = 1.f - gate;
    #pragma unroll
    for (int n = 0; n < 4; ++n) {
        #pragma unroll
        for (int j = 0; j < 4; ++j) {
            float qold = qhp[(hS + rowt[j]) * HD_DIM + n * 16 + c];
            float qn = keep * qold + gate * (pacc[n][j] + accc[n][j]) / (1.f + wsum[j]);
            Ps[wq * 16 + rg * 4 + j][n * 16 + c] = f2bf(qn * QSCALE);
        }
    }
    bf16x8_t qf2[2];
    #pragma unroll
    for (int u = 0; u < 2; ++u)
        qf2[u] = *(const bf16x8_t*)&Ps[wq * 16 + fr][u * 32 + fko];

    // ---------------- attention phase (double-buffered, no-max softmax) -----
    f32x4_t acco[4];
    #pragma unroll
    for (int n = 0; n < 4; ++n) acco[n] = (f32x4_t)0.f;
    float l_run[4] = {0.f, 0.f, 0.f, 0.f};
    {
        const u16* gk = khp + (hS + si) * HD_DIM + sdb;
        const u16* gv = vhT + (hD + si) * S_LEN + sdb;
        *(bf16x8_t*)&Ks[0][si][sdb]     = *(const bf16x8_t*)gk;
        *(bf16x8_t*)&Ks[0][si][sdb + 8] = *(const bf16x8_t*)(gk + 8);
        *(bf16x8_t*)&Xt[0][si][sdb]     = *(const bf16x8_t*)gv;
        *(bf16x8_t*)&Xt[0][si][sdb + 8] = *(const bf16x8_t*)(gv + 8);
    }
    __syncthreads();
    cur = 0;
    for (int kt = 0; kt <= qt; ++kt) {
        const int k0 = kt * KBLK;
        const bool hn = (kt < qt);
        bf16x8_t nk0, nk1, nv0, nv1;
        if (hn) {
            const u16* gk = khp + (hS + k0 + KBLK + si) * HD_DIM + sdb;
            const u16* gv = vhT + (hD + si) * S_LEN + k0 + KBLK + sdb;
            nk0 = *(const bf16x8_t*)gk; nk1 = *(const bf16x8_t*)(gk + 8);
            nv0 = *(const bf16x8_t*)gv; nv1 = *(const bf16x8_t*)(gv + 8);
        }
        f32x4_t s[4];
        #pragma unroll
        for (int n = 0; n < 4; ++n) s[n] = (f32x4_t)0.f;
        __builtin_amdgcn_s_setprio(1);
        #pragma unroll
        for (int u = 0; u < 2; ++u)
            #pragma unroll
            for (int n = 0; n < 4; ++n) {
                bf16x8_t kb = *(const bf16x8_t*)&Ks[cur][n * 16 + fr][u * 32 + fko];
                s[n] = __builtin_amdgcn_mfma_f32_16x16x32_bf16(qf2[u], kb, s[n], 0, 0, 0);
            }
        __builtin_amdgcn_s_setprio(0);
        if (kt == qt) {
            #pragma unroll
            for (int n = 0; n < 4; ++n) {
                int icol = k0 + n * 16 + c;
                #pragma unroll
                for (int j = 0; j < 4; ++j)
                    if (icol > rowt[j]) s[n][j] = -1e30f;
            }
        }
        #pragma unroll
        for (int j = 0; j < 4; ++j) {
            float p0 = exp2f(s[0][j]);
            float p1 = exp2f(s[1][j]);
            float p2 = exp2f(s[2][j]);
            float p3 = exp2f(s[3][j]);
            l_run[j] += (p0 + p1) + (p2 + p3);
            uint2 pk;
            pk.x = f2bf2(p0, p1);
            pk.y = f2bf2(p2, p3);
            *(uint2*)&Ps[wq * 16 + rg * 4 + j][c * 4] = pk;   // ds_write_b64
        }
        __builtin_amdgcn_s_setprio(1);
        #pragma unroll
        for (int u = 0; u < 2; ++u) {
            bf16x8_t pa = *(const bf16x8_t*)&Ps[wq * 16 + fr][u * 32 + fko];
            #pragma unroll
            for (int n = 0; n < 4; ++n) {
                bf16x8_t vb = *(const bf16x8_t*)&Xt[cur][n * 16 + fr][u * 32 + fko];
                acco[n] = __builtin_amdgcn_mfma_f32_16x16x32_bf16(pa, vb, acco[n], 0, 0, 0);
            }
        }
        __builtin_amdgcn_s_setprio(0);
        if (hn) {
            int nxt = cur ^ 1;
            *(bf16x8_t*)&Ks[nxt][si][sdb]     = nk0;
            *(bf16x8_t*)&Ks[nxt][si][sdb + 8] = nk1;
            *(bf16x8_t*)&Xt[nxt][si][sdb]     = nv0;
            *(bf16x8_t*)&Xt[nxt][si][sdb + 8] = nv1;
        }
        __syncthreads();
        cur ^= 1;
    }
    #pragma unroll
    for (int j = 0; j < 4; ++j) {
        l_run[j] += __shfl_xor(l_run[j], 1);
        l_run[j] += __shfl_xor(l_run[j], 2);
        l_run[j] += __shfl_xor(l_run[j], 4);
        l_run[j] += __shfl_xor(l_run[j], 8);
    }
    #pragma unroll
    for (int n = 0; n < 4; ++n) {
        #pragma unroll
        for (int j = 0; j < 4; ++j) {
            float o = acco[n][j] / l_run[j];
            ao[(size_t)rowt[j] * D_DIM + h * HD_DIM + n * 16 + c] = f2bf(o);
        }
    }
}

extern "C" void kernel_launch(void* const* d_in, const int* in_sizes, int n_in,
                              void* d_out, int out_size, void* d_ws, size_t ws_size,
                              hipStream_t stream) {
    const float* x         = (const float*)d_in[0];
    const float* norm1_w   = (const float*)d_in[1];
    const float* norm2_w   = (const float*)d_in[2];
    const float* w_qkv     = (const float*)d_in[3];
    const float* q_norm_w  = (const float*)d_in[4];
    const float* k_norm_w  = (const float*)d_in[5];
    const float* gamma_w1  = (const float*)d_in[6];
    const float* gamma_w2  = (const float*)d_in[7];
    const float* m_persist = (const float*)d_in[8];
    const float* mem_gate  = (const float*)d_in[9];
    const float* w_o       = (const float*)d_in[10];
    const float* ffn_w1    = (const float*)d_in[11];
    const float* ffn_w3    = (const float*)d_in[12];
    const float* ffn_w2    = (const float*)d_in[13];
    float* out = (float*)d_out;
    char* ws = (char*)d_ws;

    const size_t MB = 1024 * 1024;
    u16*   h_bf   = (u16*)(ws);                 // [0,4MB) h / h2
    u16*   wqT    = (u16*)(ws + 4 * MB);        // [4,10)
    u16*   woT    = (u16*)(ws + 10 * MB);       // [10,12)
    u16*   w13T   = (u16*)(ws + 12 * MB);       // [12,23) interleaved w1/w3
    u16*   w2T    = (u16*)(ws + 23 * MB);       // [23,28.5)
    u16*   qkv_bf = (u16*)(ws + 29884416);      // [28.5,40.5) dead after split
    u16*   ao_bf  = (u16*)(ws + 38273024);      // [36.5,40.5) (after qkv dead)
    float* qh     = (float*)(ws + 42467328);    // [40.5,48.5) fp32 q
    u16*   kh     = (u16*)(ws + 50855936);      // [48.5,52.5)
    u16*   khT_s  = (u16*)(ws + 50855936 + 4 * MB);   // [52.5,56.5)
    float* gammab = (float*)(ws + 59244544);    // [56.5,+8KB)
    u16*   vhT_s  = (u16*)(ws + 59244544 + 64 * 1024); // [56.5+64KB,+4MB)
    u16*   mid_bf = (u16*)(ws + 29884416);      // [28.5,40) post-attention

    // --- prep: weight transposes + rmsnorm1 + gamma, ONE launch --------------
    hipLaunchKernelGGL(prep_kernel, dim3(12544 + S_LEN), dim3(256), 0, stream,
                       w_qkv, w_o, ffn_w1, ffn_w3, ffn_w2, wqT, woT, w13T, w2T,
                       x, norm1_w, h_bf, gamma_w1, gamma_w2, gammab);

    // --- forward pass ---------------------------------------------------------
    hipLaunchKernelGGL((gemm_bb_kernel<64, 1>), dim3(24, 32), dim3(256), 0, stream,
                       h_bf, wqT, qkv_bf, S_LEN, 3 * D_DIM, D_DIM);
    hipLaunchKernelGGL(split_rope_tr_kernel, dim3(S_LEN / 64, H_NUM), dim3(256), 0, stream,
                       qkv_bf, q_norm_w, k_norm_w, qh, kh, khT_s, vhT_s);
    hipLaunchKernelGGL(fused_omega_attn_kernel, dim3(512), dim3(256), 0, stream,
                       qh, kh, khT_s, vhT_s, gammab, m_persist, mem_gate, ao_bf);
    hipLaunchKernelGGL(gemm64_kernel, dim3(16, 32), dim3(256), 0, stream,
                       ao_bf, woT, x, out, S_LEN, D_DIM, D_DIM);
    hipLaunchKernelGGL((rmsnorm_gamma_kernel<false>), dim3(S_LEN), dim3(256), 0, stream,
                       out, norm2_w, h_bf, (const float*)nullptr,
                       (const float*)nullptr, (float*)nullptr);
    // ffn13 GEMM (BM=128) with fused SwiGLU epilogue -> mid
    hipLaunchKernelGGL((gemm_bb_kernel<128, 2>), dim3(44, 16), dim3(256), 0, stream,
                       h_bf, w13T, mid_bf, S_LEN, 2 * FFNP, D_DIM);
    hipLaunchKernelGGL(gemm64_kernel, dim3(16, 32), dim3(256), 0, stream,
                       mid_bf, w2T, out, out, S_LEN, D_DIM, FFNP);
}

// Round 17
// 221.800 us; speedup vs baseline: 1.1080x; 1.0182x over previous
//
#include <hip/hip_runtime.h>
#include <hip/hip_bf16.h>

#define S_LEN 2048
#define D_DIM 1024
#define H_NUM 16
#define HD_DIM 64
#define GH_DIM 64
#define FFN_H 2730
#define FFNP  2816          // FFN_H padded to multiple of 128 (zero-filled)
#define CTX_W 512
#define L2LAM -0.00144341687f   // log2(0.999)
#define QBLK 64
#define KBLK 64
#define ALDK 76             // LDS row stride (152B): write-conflict-free, reads <=2-way
#define QSCALE 0.1803368801111731f  // 0.125 * log2(e): scores come out ready for exp2

typedef unsigned short u16;
typedef __attribute__((ext_vector_type(8))) short bf16x8_t;
typedef __attribute__((ext_vector_type(4))) float f32x4_t;

__device__ inline float wave_sum(float v) {
    for (int off = 32; off; off >>= 1) v += __shfl_xor(v, off);
    return v;
}
// f32 -> bf16 (RNE) via the HW pack instruction: 1 VALU op.
__device__ inline u16 f2bf(float f) {
    unsigned r;
    asm("v_cvt_pk_bf16_f32 %0, %1, %2" : "=v"(r) : "v"(f), "v"(f));
    return (u16)r;
}
// pack two f32 -> u32 of 2 bf16 (lo, hi): 1 VALU op.
__device__ inline unsigned f2bf2(float lo, float hi) {
    unsigned r;
    asm("v_cvt_pk_bf16_f32 %0, %1, %2" : "=v"(r) : "v"(lo), "v"(hi));
    return r;
}
__device__ inline float bf2f(u16 u) {
    return __uint_as_float(((unsigned int)u) << 16);
}
__device__ inline void gload16(const void* g, void* l) {
    __builtin_amdgcn_global_load_lds(
        (const __attribute__((address_space(1))) void*)g,
        (__attribute__((address_space(3))) void*)l, 16, 0, 0);
}

// ------- RMSNorm (fp32 in -> bf16 out), optionally fused gamma gate ---------
template<bool GAMMA>
__global__ __launch_bounds__(256) void rmsnorm_gamma_kernel(
    const float* __restrict__ in, const float* __restrict__ w,
    u16* __restrict__ out, const float* __restrict__ w1,
    const float* __restrict__ w2, float* __restrict__ gamma)
{
    __shared__ float hl[D_DIM];
    __shared__ float part[4][GH_DIM];
    __shared__ float wsum[4];
    int row = blockIdx.x;
    int tid = threadIdx.x, lane = tid & 63, wv = tid >> 6;
    const float4* ir = reinterpret_cast<const float4*>(in + (size_t)row * D_DIM);
    float4 v = ir[tid];
    float ss = v.x*v.x + v.y*v.y + v.z*v.z + v.w*v.w;
    ss = wave_sum(ss);
    if (lane == 0) wsum[wv] = ss;
    __syncthreads();
    float tot = wsum[0] + wsum[1] + wsum[2] + wsum[3];
    float scale = rsqrtf(tot / (float)D_DIM + 1e-6f);
    const float4* wr = reinterpret_cast<const float4*>(w);
    float4 wv4 = wr[tid];
    float h0 = v.x * scale * wv4.x, h1 = v.y * scale * wv4.y;
    float h2 = v.z * scale * wv4.z, h3 = v.w * scale * wv4.w;
    uint2 o;
    o.x = f2bf2(h0, h1);
    o.y = f2bf2(h2, h3);
    *reinterpret_cast<uint2*>(out + (size_t)row * D_DIM + tid * 4) = o;
    if (GAMMA) {
        hl[tid*4+0] = h0; hl[tid*4+1] = h1; hl[tid*4+2] = h2; hl[tid*4+3] = h3;
        __syncthreads();
        float acc = 0.f;
        #pragma unroll 8
        for (int k = wv * 256; k < wv * 256 + 256; ++k)
            acc += hl[k] * w1[k * GH_DIM + lane];
        part[wv][lane] = acc;
        __syncthreads();
        if (wv == 0) {
            float t = part[0][lane] + part[1][lane] + part[2][lane] + part[3][lane];
            float z = t / (1.f + __expf(-t));
            float y = z * w2[lane];
            float t2 = wave_sum(y);
            if (lane == 0) gamma[row] = 1.f / (1.f + __expf(-t2));
        }
    }
}

// --- prep: weight transposes (64x64 tiles, 128B writes) + rmsnorm1+gamma ----
// Blocks [0,3136) transpose the 5 weight segments; [3136,5184) do
// rmsnorm1+gamma for row = b-3136.
__global__ __launch_bounds__(256) void prep_kernel(
    const float* __restrict__ w_qkv, const float* __restrict__ w_o,
    const float* __restrict__ w1f, const float* __restrict__ w3f,
    const float* __restrict__ w2f, u16* __restrict__ wqT,
    u16* __restrict__ woT, u16* __restrict__ w13T, u16* __restrict__ w2T,
    const float* __restrict__ x, const float* __restrict__ norm1_w,
    u16* __restrict__ h_bf, const float* __restrict__ gw1,
    const float* __restrict__ gw2, float* __restrict__ gamma)
{
    __shared__ float tile[64][65];
    __shared__ float part[4][GH_DIM];
    __shared__ float wsum[4];
    int b = blockIdx.x;
    int tid = threadIdx.x;
    if (b < 3136) {
        const float* src; u16* dst;
        int srcK, srcN, Kp, rowOff, rowMul, nbx;
        if (b < 768)       {           src = w_qkv; dst = wqT;  srcK = 1024; srcN = 3072; Kp = 1024; rowOff = 0; rowMul = 1; nbx = 48; }
        else if (b < 1024) { b -= 768;  src = w_o;  dst = woT;  srcK = 1024; srcN = 1024; Kp = 1024; rowOff = 0; rowMul = 1; nbx = 16; }
        else if (b < 1728) { b -= 1024; src = w1f;  dst = w13T; srcK = 1024; srcN = 2730; Kp = 1024; rowOff = 0; rowMul = 2; nbx = 44; }
        else if (b < 2432) { b -= 1728; src = w3f;  dst = w13T; srcK = 1024; srcN = 2730; Kp = 1024; rowOff = 1; rowMul = 2; nbx = 44; }
        else               { b -= 2432; src = w2f;  dst = w2T;  srcK = 2730; srcN = 1024; Kp = 2816; rowOff = 0; rowMul = 1; nbx = 16; }
        int n0 = (b % nbx) * 64, k0 = (b / nbx) * 64;
        int tx = tid & 15, ty = tid >> 4;       // read: 16 thr/row x float4
        bool interior = (k0 + 63 < srcK) && (n0 + 63 < srcN);
        #pragma unroll
        for (int p = 0; p < 4; ++p) {
            int kk = p * 16 + ty;
            int r = k0 + kk;
            int cb = n0 + tx * 4;
            float4 v;
            if (interior) {
                v = *(const float4*)(src + (size_t)r * srcN + cb);
            } else {
                v.x = (r < srcK && cb     < srcN) ? src[(size_t)r * srcN + cb]     : 0.f;
                v.y = (r < srcK && cb + 1 < srcN) ? src[(size_t)r * srcN + cb + 1] : 0.f;
                v.z = (r < srcK && cb + 2 < srcN) ? src[(size_t)r * srcN + cb + 2] : 0.f;
                v.w = (r < srcK && cb + 3 < srcN) ? src[(size_t)r * srcN + cb + 3] : 0.f;
            }
            tile[kk][tx*4+0] = v.x; tile[kk][tx*4+1] = v.y;
            tile[kk][tx*4+2] = v.z; tile[kk][tx*4+3] = v.w;
        }
        __syncthreads();
        int wx = tid & 7, wy = tid >> 3;        // write: 8 thr/row x uint4(8 u16)
        #pragma unroll
        for (int p = 0; p < 2; ++p) {
            int nn = p * 32 + wy;
            int ks = wx * 8;
            uint4 o;
            o.x = f2bf2(tile[ks+0][nn], tile[ks+1][nn]);
            o.y = f2bf2(tile[ks+2][nn], tile[ks+3][nn]);
            o.z = f2bf2(tile[ks+4][nn], tile[ks+5][nn]);
            o.w = f2bf2(tile[ks+6][nn], tile[ks+7][nn]);
            *(uint4*)(dst + (size_t)(rowOff + (size_t)(n0 + nn) * rowMul) * Kp + k0 + ks) = o;
        }
    } else {
        int row = b - 3136;
        int lane = tid & 63, wv = tid >> 6;
        float* hl = &tile[0][0];    // reuse LDS (4KB of the 16.6KB tile)
        const float4* ir = reinterpret_cast<const float4*>(x + (size_t)row * D_DIM);
        float4 v = ir[tid];
        float ss = v.x*v.x + v.y*v.y + v.z*v.z + v.w*v.w;
        ss = wave_sum(ss);
        if (lane == 0) wsum[wv] = ss;
        __syncthreads();
        float tot = wsum[0] + wsum[1] + wsum[2] + wsum[3];
        float scale = rsqrtf(tot / (float)D_DIM + 1e-6f);
        const float4* wr = reinterpret_cast<const float4*>(norm1_w);
        float4 wv4 = wr[tid];
        float h0 = v.x * scale * wv4.x, h1 = v.y * scale * wv4.y;
        float h2 = v.z * scale * wv4.z, h3 = v.w * scale * wv4.w;
        uint2 o;
        o.x = f2bf2(h0, h1);
        o.y = f2bf2(h2, h3);
        *reinterpret_cast<uint2*>(h_bf + (size_t)row * D_DIM + tid * 4) = o;
        hl[tid*4+0] = h0; hl[tid*4+1] = h1; hl[tid*4+2] = h2; hl[tid*4+3] = h3;
        __syncthreads();
        float acc = 0.f;
        #pragma unroll 8
        for (int k = wv * 256; k < wv * 256 + 256; ++k)
            acc += hl[k] * gw1[k * GH_DIM + lane];
        part[wv][lane] = acc;
        __syncthreads();
        if (wv == 0) {
            float t = part[0][lane] + part[1][lane] + part[2][lane] + part[3][lane];
            float z = t / (1.f + __expf(-t));
            float y = z * gw2[lane];
            float t2 = wave_sum(y);
            if (lane == 0) gamma[row] = 1.f / (1.f + __expf(-t2));
        }
    }
}

// ---- fused split qkv + qk rmsnorm + RoPE + KV transpose (one launch) -------
__global__ __launch_bounds__(256) void split_rope_tr_kernel(
    const u16* __restrict__ qkv, const float* __restrict__ qw,
    const float* __restrict__ kw, float* __restrict__ qhp,
    u16* __restrict__ khp, u16* __restrict__ khT, u16* __restrict__ vhT)
{
    __shared__ u16 tk[64][ALDK];
    __shared__ u16 tv[64][ALDK];
    int tid = threadIdx.x;
    int w = tid >> 6, d = tid & 63;
    int h = blockIdx.y;
    int s0 = blockIdx.x * 64;
    float qwv = qw[d], kwv = kw[d];
    int j = d & 31;
    float inv = expf(-(float)j * (9.2103403719761836f / 32.0f));
    float sgn = (d < 32) ? -1.f : 1.f;
    for (int i = 0; i < 16; ++i) {
        int sl = w * 16 + i;
        int s = s0 + sl;
        size_t base = (size_t)s * (3 * D_DIM) + h * HD_DIM + d;
        float qv = bf2f(qkv[base]);
        float kv = bf2f(qkv[base + D_DIM]);
        u16  vv = qkv[base + 2 * D_DIM];
        float sq = wave_sum(qv * qv);
        float qn = qv * rsqrtf(sq / (float)HD_DIM + 1e-6f) * qwv;
        float sk = wave_sum(kv * kv);
        float kn = kv * rsqrtf(sk / (float)HD_DIM + 1e-6f) * kwv;
        float ang = (float)s * inv;
        float cs = cosf(ang), sn = sinf(ang);
        float qp = __shfl_xor(qn, 32);
        float kp = __shfl_xor(kn, 32);
        float qo = qn * cs + sgn * qp * sn;
        float ko = kn * cs + sgn * kp * sn;
        size_t ob = ((size_t)h * S_LEN + s) * HD_DIM + d;
        u16 kb = f2bf(ko);
        qhp[ob] = qo;
        khp[ob] = kb;
        tk[sl][d] = kb;
        tv[sl][d] = vv;
    }
    __syncthreads();
    int r = tid >> 2, cc = (tid & 3) * 16;
    union { u16 u[16]; bf16x8_t v[2]; } ok, ov;
    #pragma unroll
    for (int e = 0; e < 16; ++e) {
        int ksrc = (e & 3) * 16 + (tid & 3) * 4 + (e >> 2);   // pi^-1 permute
        ok.u[e] = tk[ksrc][r]; ov.u[e] = tv[ksrc][r];
    }
    u16* kd = khT + ((size_t)h * HD_DIM + r) * S_LEN + s0 + cc;
    u16* vd = vhT + ((size_t)h * HD_DIM + r) * S_LEN + s0 + cc;
    *(bf16x8_t*)kd       = ok.v[0];
    *(bf16x8_t*)(kd + 8) = ok.v[1];
    *(bf16x8_t*)vd       = ov.v[0];
    *(bf16x8_t*)(vd + 8) = ov.v[1];
}

// ---------------- bf16 MFMA GEMM, 128-col tiles ------------------------------
// MODE 1: bf16 out.  MODE 2: paired silu-mul, bf16 out width N/2.
template<int BM, int MODE>
__global__ __launch_bounds__(256) void gemm_bb_kernel(
    const u16* __restrict__ A, const u16* __restrict__ B,
    u16* __restrict__ Cb, int M, int N, int K)
{
    constexpr int MREP = BM / 32;
    constexpr int ACH  = BM / 32;
    __shared__ u16 As[BM * 64];
    __shared__ u16 Bs[128 * 64];
    int tid = threadIdx.x, lane = tid & 63, wid = tid >> 6;
    int wr = wid >> 1, wc = wid & 1;
    int row0 = blockIdx.y * BM, col0 = blockIdx.x * 128;
    int l8 = lane >> 3, l7 = lane & 7;
    f32x4_t acc[MREP][4];
    #pragma unroll
    for (int i = 0; i < MREP; ++i)
        #pragma unroll
        for (int j = 0; j < 4; ++j) acc[i][j] = (f32x4_t)0.f;

    int fr = lane & 15, fo = (lane >> 4) * 8;
    for (int k0 = 0; k0 < K; k0 += 64) {
        #pragma unroll
        for (int i = 0; i < ACH; ++i) {
            int ch = wid * ACH + i;
            const u16* ga = A + (size_t)(row0 + ch * 8 + l8) * K + k0 + l7 * 8;
            gload16(ga, &As[ch * 512]);
        }
        #pragma unroll
        for (int i = 0; i < 4; ++i) {
            int ch = wid * 4 + i;
            const u16* gb = B + (size_t)(col0 + ch * 8 + l8) * K + k0 + l7 * 8;
            gload16(gb, &Bs[ch * 512]);
        }
        __syncthreads();
        __builtin_amdgcn_s_setprio(1);
        #pragma unroll
        for (int khf = 0; khf < 2; ++khf) {
            bf16x8_t bfrag[4];
            #pragma unroll
            for (int ni = 0; ni < 4; ++ni)
                bfrag[ni] = *(const bf16x8_t*)&Bs[(wc * 64 + ni * 16 + fr) * 64 + khf * 32 + fo];
            #pragma unroll
            for (int mi = 0; mi < MREP; ++mi) {
                bf16x8_t af = *(const bf16x8_t*)&As[(wr * (BM / 2) + mi * 16 + fr) * 64 + khf * 32 + fo];
                #pragma unroll
                for (int ni = 0; ni < 4; ++ni)
                    acc[mi][ni] = __builtin_amdgcn_mfma_f32_16x16x32_bf16(
                        af, bfrag[ni], acc[mi][ni], 0, 0, 0);
            }
        }
        __builtin_amdgcn_s_setprio(0);
        __syncthreads();
    }
    int dr = (lane >> 4) * 4, dc = lane & 15;
    #pragma unroll
    for (int mi = 0; mi < MREP; ++mi) {
        int gr = row0 + wr * (BM / 2) + mi * 16 + dr;
        #pragma unroll
        for (int ni = 0; ni < 4; ++ni) {
            int gc = col0 + wc * 64 + ni * 16 + dc;
            #pragma unroll
            for (int j = 0; j < 4; ++j) {
                float v = acc[mi][ni][j];
                if (MODE == 1) {
                    Cb[(size_t)(gr + j) * N + gc] = f2bf(v);
                } else {
                    float partner = __shfl_xor(v, 1);
                    float a1 = (dc & 1) ? partner : v;
                    float a3 = (dc & 1) ? v : partner;
                    float rr = a1 / (1.f + __expf(-a1)) * a3;
                    if (!(dc & 1))
                        Cb[(size_t)(gr + j) * (N >> 1) + (gc >> 1)] = f2bf(rr);
                }
            }
        }
    }
}

// ---------------- bf16 MFMA GEMM, 64x64 tiles, fp32 out + residual ----------
__global__ __launch_bounds__(256) void gemm64_kernel(
    const u16* __restrict__ A, const u16* __restrict__ B,
    const float* __restrict__ res, float* __restrict__ Cf,
    int M, int N, int K)
{
    __shared__ u16 As[64 * 64];
    __shared__ u16 Bs[64 * 64];
    int tid = threadIdx.x, lane = tid & 63, wid = tid >> 6;
    int wr = wid >> 1, wc = wid & 1;
    int row0 = blockIdx.y * 64, col0 = blockIdx.x * 64;
    int l8 = lane >> 3, l7 = lane & 7;
    f32x4_t acc[2][2];
    #pragma unroll
    for (int i = 0; i < 2; ++i)
        #pragma unroll
        for (int j = 0; j < 2; ++j) acc[i][j] = (f32x4_t)0.f;
    int fr = lane & 15, fo = (lane >> 4) * 8;
    for (int k0 = 0; k0 < K; k0 += 64) {
        #pragma unroll
        for (int i = 0; i < 2; ++i) {
            int ch = wid * 2 + i;
            const u16* ga = A + (size_t)(row0 + ch * 8 + l8) * K + k0 + l7 * 8;
            gload16(ga, &As[ch * 512]);
            const u16* gb = B + (size_t)(col0 + ch * 8 + l8) * K + k0 + l7 * 8;
            gload16(gb, &Bs[ch * 512]);
        }
        __syncthreads();
        __builtin_amdgcn_s_setprio(1);
        #pragma unroll
        for (int khf = 0; khf < 2; ++khf) {
            bf16x8_t bfrag[2];
            #pragma unroll
            for (int ni = 0; ni < 2; ++ni)
                bfrag[ni] = *(const bf16x8_t*)&Bs[(wc * 32 + ni * 16 + fr) * 64 + khf * 32 + fo];
            #pragma unroll
            for (int mi = 0; mi < 2; ++mi) {
                bf16x8_t af = *(const bf16x8_t*)&As[(wr * 32 + mi * 16 + fr) * 64 + khf * 32 + fo];
                #pragma unroll
                for (int ni = 0; ni < 2; ++ni)
                    acc[mi][ni] = __builtin_amdgcn_mfma_f32_16x16x32_bf16(
                        af, bfrag[ni], acc[mi][ni], 0, 0, 0);
            }
        }
        __builtin_amdgcn_s_setprio(0);
        __syncthreads();
    }
    int dr = (lane >> 4) * 4, dc = lane & 15;
    #pragma unroll
    for (int mi = 0; mi < 2; ++mi) {
        int gr = row0 + wr * 32 + mi * 16 + dr;
        #pragma unroll
        for (int ni = 0; ni < 2; ++ni) {
            int gc = col0 + wc * 32 + ni * 16 + dc;
            #pragma unroll
            for (int j = 0; j < 4; ++j) {
                size_t off = (size_t)(gr + j) * N + gc;
                Cf[off] = acc[mi][ni][j] + res[off];
            }
        }
    }
}

// ============ FUSED omega-rule + flash attention ============================
__global__ __launch_bounds__(256) void fused_omega_attn_kernel(
    const float* __restrict__ qhp, const u16* __restrict__ khp,
    const u16* __restrict__ khT, const u16* __restrict__ vhT,
    const float* __restrict__ gammab, const float* __restrict__ mp,
    const float* __restrict__ mg, u16* __restrict__ ao)
{
    __shared__ u16 Ks[2][KBLK][ALDK];
    __shared__ u16 Xt[2][KBLK][ALDK];
    __shared__ u16 Ps[QBLK][ALDK];
    __shared__ float colfL[CTX_W + KBLK];
    const int tid = threadIdx.x, lane = tid & 63, wq = tid >> 6;
    const int b = blockIdx.x;
    const int hi = (b >> 8) & 1;
    const int h = ((b & 7) << 1) + hi;
    const int s5 = (b >> 3) & 31;
    const int qt = hi ? (31 - s5) : s5;
    const int q0 = qt * QBLK;
    const int fr = lane & 15, g4 = lane >> 4;
    const int fko = g4 * 8;
    const int c = fr, rg = g4;
    const int si = tid >> 2, sdb = (tid & 3) * 16;
    const size_t hS = (size_t)h * S_LEN;
    const size_t hD = (size_t)h * HD_DIM;

    int rowt[4]; float rowf[4];
    #pragma unroll
    for (int j = 0; j < 4; ++j) {
        rowt[j] = q0 + wq * 16 + rg * 4 + j;
        rowf[j] = exp2f((float)(wq * 16 + rg * 4 + j) * L2LAM);
    }
    bf16x8_t qf[2];
    {
        const float* qrow = qhp + (hS + q0 + wq * 16 + fr) * HD_DIM;
        #pragma unroll
        for (int u = 0; u < 2; ++u) {
            float4 a = *(const float4*)(qrow + u * 32 + fko);
            float4 bq = *(const float4*)(qrow + u * 32 + fko + 4);
            bf16x8_t f;
            f[0]=f2bf(a.x); f[1]=f2bf(a.y); f[2]=f2bf(a.z); f[3]=f2bf(a.w);
            f[4]=f2bf(bq.x); f[5]=f2bf(bq.y); f[6]=f2bf(bq.z); f[7]=f2bf(bq.w);
            qf[u] = f;
        }
    }
    // ---------------- omega phase (double-buffered) ----------------
    f32x4_t accc[4];
    #pragma unroll
    for (int n = 0; n < 4; ++n) accc[n] = (f32x4_t)0.f;
    float wsum[4] = {0.f, 0.f, 0.f, 0.f};
    const int kt0 = (q0 > (CTX_W - 1)) ? (q0 - (CTX_W - 1)) / KBLK : 0;
    const int i0 = kt0 * KBLK;
    const int nwin = (qt + 1) * KBLK - i0;
    for (int idx = tid; idx < nwin; idx += 256) {
        int icol = i0 + idx;
        colfL[idx] = exp2f((float)(q0 - icol) * L2LAM) * gammab[icol];
    }
    {
        const u16* gk = khp + (hS + kt0 * KBLK + si) * HD_DIM + sdb;
        const u16* gx = khT + (hD + si) * S_LEN + kt0 * KBLK + sdb;
        *(bf16x8_t*)&Ks[0][si][sdb]     = *(const bf16x8_t*)gk;
        *(bf16x8_t*)&Ks[0][si][sdb + 8] = *(const bf16x8_t*)(gk + 8);
        *(bf16x8_t*)&Xt[0][si][sdb]     = *(const bf16x8_t*)gx;
        *(bf16x8_t*)&Xt[0][si][sdb + 8] = *(const bf16x8_t*)(gx + 8);
    }
    __syncthreads();
    int cur = 0;
    for (int kt = kt0; kt <= qt; ++kt) {
        const int k0 = kt * KBLK;
        const bool hn = (kt < qt);
        bf16x8_t nk0, nk1, nx0, nx1;
        if (hn) {
            const u16* gk = khp + (hS + k0 + KBLK + si) * HD_DIM + sdb;
            const u16* gx = khT + (hD + si) * S_LEN + k0 + KBLK + sdb;
            nk0 = *(const bf16x8_t*)gk; nk1 = *(const bf16x8_t*)(gk + 8);
            nx0 = *(const bf16x8_t*)gx; nx1 = *(const bf16x8_t*)(gx + 8);
        }
        f32x4_t s[4];
        #pragma unroll
        for (int n = 0; n < 4; ++n) s[n] = (f32x4_t)0.f;
        __builtin_amdgcn_s_setprio(1);
        #pragma unroll
        for (int u = 0; u < 2; ++u)
            #pragma unroll
            for (int n = 0; n < 4; ++n) {
                bf16x8_t kb = *(const bf16x8_t*)&Ks[cur][n * 16 + fr][u * 32 + fko];
                s[n] = __builtin_amdgcn_mfma_f32_16x16x32_bf16(qf[u], kb, s[n], 0, 0, 0);
            }
        __builtin_amdgcn_s_setprio(0);
        const bool boundary = (kt == kt0) || (kt == qt);
        float colf[4];
        #pragma unroll
        for (int n = 0; n < 4; ++n)
            colf[n] = colfL[k0 - i0 + n * 16 + c];
        #pragma unroll
        for (int j = 0; j < 4; ++j) {
            float pv[4];
            #pragma unroll
            for (int n = 0; n < 4; ++n) {
                float w;
                if (boundary) {
                    int delta = rowt[j] - (k0 + n * 16 + c);
                    w = (delta >= 0 && delta < CTX_W) ? rowf[j] * colf[n] : 0.f;
                } else {
                    w = rowf[j] * colf[n];
                }
                wsum[j] += w;
                pv[n] = w * s[n][j];
            }
            uint2 pk;
            pk.x = f2bf2(pv[0], pv[1]);
            pk.y = f2bf2(pv[2], pv[3]);
            *(uint2*)&Ps[wq * 16 + rg * 4 + j][c * 4] = pk;   // ds_write_b64
        }
        __builtin_amdgcn_s_setprio(1);
        #pragma unroll
        for (int u = 0; u < 2; ++u) {
            bf16x8_t pa = *(const bf16x8_t*)&Ps[wq * 16 + fr][u * 32 + fko];
            #pragma unroll
            for (int n = 0; n < 4; ++n) {
                bf16x8_t kb = *(const bf16x8_t*)&Xt[cur][n * 16 + fr][u * 32 + fko];
                accc[n] = __builtin_amdgcn_mfma_f32_16x16x32_bf16(pa, kb, accc[n], 0, 0, 0);
            }
        }
        __builtin_amdgcn_s_setprio(0);
        if (hn) {
            int nxt = cur ^ 1;
            *(bf16x8_t*)&Ks[nxt][si][sdb]     = nk0;
            *(bf16x8_t*)&Ks[nxt][si][sdb + 8] = nk1;
            *(bf16x8_t*)&Xt[nxt][si][sdb]     = nx0;
            *(bf16x8_t*)&Xt[nxt][si][sdb + 8] = nx1;
        }
        __syncthreads();
        cur ^= 1;
    }
    // persist = Q @ M_p^T
    f32x4_t pacc[4];
    #pragma unroll
    for (int n = 0; n < 4; ++n) pacc[n] = (f32x4_t)0.f;
    const float* mph = mp + hD * HD_DIM;
    #pragma unroll
    for (int u = 0; u < 2; ++u)
        #pragma unroll
        for (int n = 0; n < 4; ++n) {
            const float* br = mph + (size_t)(n * 16 + fr) * HD_DIM + u * 32 + fko;
            float4 a = *(const float4*)br;
            float4 bq = *(const float4*)(br + 4);
            bf16x8_t f;
            f[0]=f2bf(a.x); f[1]=f2bf(a.y); f[2]=f2bf(a.z); f[3]=f2bf(a.w);
            f[4]=f2bf(bq.x); f[5]=f2bf(bq.y); f[6]=f2bf(bq.z); f[7]=f2bf(bq.w);
            pacc[n] = __builtin_amdgcn_mfma_f32_16x16x32_bf16(qf[u], f, pacc[n], 0, 0, 0);
        }
    #pragma unroll
    for (int j = 0; j < 4; ++j) {
        wsum[j] += __shfl_xor(wsum[j], 1);
        wsum[j] += __shfl_xor(wsum[j], 2);
        wsum[j] += __shfl_xor(wsum[j], 4);
        wsum[j] += __shfl_xor(wsum[j], 8);
    }
    float gate = 1.f / (1.f + __expf(-mg[0]));
    float keep = 1.f - gate;
    #pragma unroll
    for (int n = 0; n < 4; ++n) {
        #pragma unroll
        for (int j = 0; j < 4; ++j) {
            float qold = qhp[(hS + rowt[j]) * HD_DIM + n * 16 + c];
            float qn = keep * qold + gate * (pacc[n][j] + accc[n][j]) / (1.f + wsum[j]);
            Ps[wq * 16 + rg * 4 + j][n * 16 + c] = f2bf(qn * QSCALE);
        }
    }
    bf16x8_t qf2[2];
    #pragma unroll
    for (int u = 0; u < 2; ++u)
        qf2[u] = *(const bf16x8_t*)&Ps[wq * 16 + fr][u * 32 + fko];

    // ---------------- attention phase (double-buffered, no-max softmax) -----
    f32x4_t acco[4];
    #pragma unroll
    for (int n = 0; n < 4; ++n) acco[n] = (f32x4_t)0.f;
    float l_run[4] = {0.f, 0.f, 0.f, 0.f};
    {
        const u16* gk = khp + (hS + si) * HD_DIM + sdb;
        const u16* gv = vhT + (hD + si) * S_LEN + sdb;
        *(bf16x8_t*)&Ks[0][si][sdb]     = *(const bf16x8_t*)gk;
        *(bf16x8_t*)&Ks[0][si][sdb + 8] = *(const bf16x8_t*)(gk + 8);
        *(bf16x8_t*)&Xt[0][si][sdb]     = *(const bf16x8_t*)gv;
        *(bf16x8_t*)&Xt[0][si][sdb + 8] = *(const bf16x8_t*)(gv + 8);
    }
    __syncthreads();
    cur = 0;
    for (int kt = 0; kt <= qt; ++kt) {
        const int k0 = kt * KBLK;
        const bool hn = (kt < qt);
        bf16x8_t nk0, nk1, nv0, nv1;
        if (hn) {
            const u16* gk = khp + (hS + k0 + KBLK + si) * HD_DIM + sdb;
            const u16* gv = vhT + (hD + si) * S_LEN + k0 + KBLK + sdb;
            nk0 = *(const bf16x8_t*)gk; nk1 = *(const bf16x8_t*)(gk + 8);
            nv0 = *(const bf16x8_t*)gv; nv1 = *(const bf16x8_t*)(gv + 8);
        }
        f32x4_t s[4];
        #pragma unroll
        for (int n = 0; n < 4; ++n) s[n] = (f32x4_t)0.f;
        __builtin_amdgcn_s_setprio(1);
        #pragma unroll
        for (int u = 0; u < 2; ++u)
            #pragma unroll
            for (int n = 0; n < 4; ++n) {
                bf16x8_t kb = *(const bf16x8_t*)&Ks[cur][n * 16 + fr][u * 32 + fko];
                s[n] = __builtin_amdgcn_mfma_f32_16x16x32_bf16(qf2[u], kb, s[n], 0, 0, 0);
            }
        __builtin_amdgcn_s_setprio(0);
        if (kt == qt) {
            #pragma unroll
            for (int n = 0; n < 4; ++n) {
                int icol = k0 + n * 16 + c;
                #pragma unroll
                for (int j = 0; j < 4; ++j)
                    if (icol > rowt[j]) s[n][j] = -1e30f;
            }
        }
        #pragma unroll
        for (int j = 0; j < 4; ++j) {
            float p0 = exp2f(s[0][j]);
            float p1 = exp2f(s[1][j]);
            float p2 = exp2f(s[2][j]);
            float p3 = exp2f(s[3][j]);
            l_run[j] += (p0 + p1) + (p2 + p3);
            uint2 pk;
            pk.x = f2bf2(p0, p1);
            pk.y = f2bf2(p2, p3);
            *(uint2*)&Ps[wq * 16 + rg * 4 + j][c * 4] = pk;   // ds_write_b64
        }
        __builtin_amdgcn_s_setprio(1);
        #pragma unroll
        for (int u = 0; u < 2; ++u) {
            bf16x8_t pa = *(const bf16x8_t*)&Ps[wq * 16 + fr][u * 32 + fko];
            #pragma unroll
            for (int n = 0; n < 4; ++n) {
                bf16x8_t vb = *(const bf16x8_t*)&Xt[cur][n * 16 + fr][u * 32 + fko];
                acco[n] = __builtin_amdgcn_mfma_f32_16x16x32_bf16(pa, vb, acco[n], 0, 0, 0);
            }
        }
        __builtin_amdgcn_s_setprio(0);
        if (hn) {
            int nxt = cur ^ 1;
            *(bf16x8_t*)&Ks[nxt][si][sdb]     = nk0;
            *(bf16x8_t*)&Ks[nxt][si][sdb + 8] = nk1;
            *(bf16x8_t*)&Xt[nxt][si][sdb]     = nv0;
            *(bf16x8_t*)&Xt[nxt][si][sdb + 8] = nv1;
        }
        __syncthreads();
        cur ^= 1;
    }
    #pragma unroll
    for (int j = 0; j < 4; ++j) {
        l_run[j] += __shfl_xor(l_run[j], 1);
        l_run[j] += __shfl_xor(l_run[j], 2);
        l_run[j] += __shfl_xor(l_run[j], 4);
        l_run[j] += __shfl_xor(l_run[j], 8);
    }
    #pragma unroll
    for (int n = 0; n < 4; ++n) {
        #pragma unroll
        for (int j = 0; j < 4; ++j) {
            float o = acco[n][j] / l_run[j];
            ao[(size_t)rowt[j] * D_DIM + h * HD_DIM + n * 16 + c] = f2bf(o);
        }
    }
}

extern "C" void kernel_launch(void* const* d_in, const int* in_sizes, int n_in,
                              void* d_out, int out_size, void* d_ws, size_t ws_size,
                              hipStream_t stream) {
    const float* x         = (const float*)d_in[0];
    const float* norm1_w   = (const float*)d_in[1];
    const float* norm2_w   = (const float*)d_in[2];
    const float* w_qkv     = (const float*)d_in[3];
    const float* q_norm_w  = (const float*)d_in[4];
    const float* k_norm_w  = (const float*)d_in[5];
    const float* gamma_w1  = (const float*)d_in[6];
    const float* gamma_w2  = (const float*)d_in[7];
    const float* m_persist = (const float*)d_in[8];
    const float* mem_gate  = (const float*)d_in[9];
    const float* w_o       = (const float*)d_in[10];
    const float* ffn_w1    = (const float*)d_in[11];
    const float* ffn_w3    = (const float*)d_in[12];
    const float* ffn_w2    = (const float*)d_in[13];
    float* out = (float*)d_out;
    char* ws = (char*)d_ws;

    const size_t MB = 1024 * 1024;
    u16*   h_bf   = (u16*)(ws);                 // [0,4MB) h / h2
    u16*   wqT    = (u16*)(ws + 4 * MB);        // [4,10)
    u16*   woT    = (u16*)(ws + 10 * MB);       // [10,12)
    u16*   w13T   = (u16*)(ws + 12 * MB);       // [12,23) interleaved w1/w3
    u16*   w2T    = (u16*)(ws + 23 * MB);       // [23,28.5)
    u16*   qkv_bf = (u16*)(ws + 29884416);      // [28.5,40.5) dead after split
    u16*   ao_bf  = (u16*)(ws + 38273024);      // [36.5,40.5) (after qkv dead)
    float* qh     = (float*)(ws + 42467328);    // [40.5,48.5) fp32 q
    u16*   kh     = (u16*)(ws + 50855936);      // [48.5,52.5)
    u16*   khT_s  = (u16*)(ws + 50855936 + 4 * MB);   // [52.5,56.5)
    float* gammab = (float*)(ws + 59244544);    // [56.5,+8KB)
    u16*   vhT_s  = (u16*)(ws + 59244544 + 64 * 1024); // [56.5+64KB,+4MB)
    u16*   mid_bf = (u16*)(ws + 29884416);      // [28.5,40) post-attention

    // --- prep: weight transposes + rmsnorm1 + gamma, ONE launch --------------
    hipLaunchKernelGGL(prep_kernel, dim3(3136 + S_LEN), dim3(256), 0, stream,
                       w_qkv, w_o, ffn_w1, ffn_w3, ffn_w2, wqT, woT, w13T, w2T,
                       x, norm1_w, h_bf, gamma_w1, gamma_w2, gammab);

    // --- forward pass ---------------------------------------------------------
    hipLaunchKernelGGL((gemm_bb_kernel<64, 1>), dim3(24, 32), dim3(256), 0, stream,
                       h_bf, wqT, qkv_bf, S_LEN, 3 * D_DIM, D_DIM);
    hipLaunchKernelGGL(split_rope_tr_kernel, dim3(S_LEN / 64, H_NUM), dim3(256), 0, stream,
                       qkv_bf, q_norm_w, k_norm_w, qh, kh, khT_s, vhT_s);
    hipLaunchKernelGGL(fused_omega_attn_kernel, dim3(512), dim3(256), 0, stream,
                       qh, kh, khT_s, vhT_s, gammab, m_persist, mem_gate, ao_bf);
    hipLaunchKernelGGL(gemm64_kernel, dim3(16, 32), dim3(256), 0, stream,
                       ao_bf, woT, x, out, S_LEN, D_DIM, D_DIM);
    hipLaunchKernelGGL((rmsnorm_gamma_kernel<false>), dim3(S_LEN), dim3(256), 0, stream,
                       out, norm2_w, h_bf, (const float*)nullptr,
                       (const float*)nullptr, (float*)nullptr);
    // ffn13 GEMM (BM=128) with fused SwiGLU epilogue -> mid
    hipLaunchKernelGGL((gemm_bb_kernel<128, 2>), dim3(44, 16), dim3(256), 0, stream,
                       h_bf, w13T, mid_bf, S_LEN, 2 * FFNP, D_DIM);
    hipLaunchKernelGGL(gemm64_kernel, dim3(16, 32), dim3(256), 0, stream,
                       mid_bf, w2T, out, out, S_LEN, D_DIM, FFNP);
}